// Round 5
// baseline (443.540 us; speedup 1.0000x reference)
//
#include <hip/hip_runtime.h>
#include <hip/hip_bf16.h>
#include <stdint.h>
#include <stddef.h>

// ---------------------------------------------------------------------------
// NonLocalBlock2D: B=8, C=256, H=W=64 (N=4096), CI=128
// out = x + Wout * softmax( (theta(x)^T phi(x)) * sqrt(CI) ) * g(x)
// Split-fp32 (bf16 hi+lo, 3-MFMA) upstream of softmax; plain bf16 after.
// theta pre-scaled by sqrt(128)/ln2 -> softmax in exp2 domain.
// V stored transposed [b][ci][n].
// k_attn_sp: NO LDS staging for K/V -- MFMA fragments read directly from
// global (L2-resident per-XCD working set, b = bid&7 colocation). LDS holds
// only the per-wave P buffer => zero barriers in the main loop.
// ---------------------------------------------------------------------------

typedef __bf16 bf16;
typedef __attribute__((ext_vector_type(8))) __bf16 bf16x8;
typedef __attribute__((ext_vector_type(4))) __bf16 bf16x4;
typedef __attribute__((ext_vector_type(4))) float  f32x4;
typedef __attribute__((ext_vector_type(4))) int    i32x4;

#define MFMA16(a, b, c) __builtin_amdgcn_mfma_f32_16x16x32_bf16((a), (b), (c), 0, 0, 0)

constexpr int NB  = 8;
constexpr int NC  = 256;
constexpr int NN  = 4096;
constexpr int NCI = 128;
constexpr size_t NEL = (size_t)NB * NN * NCI;

// sqrt(128) / ln(2): folded into theta so logits are in log2 units.
#define QSCALE (11.313708498984761f * 1.4426950408889634f)

// ---------------------------------------------------------------------------
// Kernel 1: projections.  pj=0 -> theta*QSCALE (split qh/ql),
// pj=1 -> phi (split kh/kl), pj=2 -> g stored transposed vv[b][i][n].
// ---------------------------------------------------------------------------
__global__ __launch_bounds__(256) void k_proj(
    const float* __restrict__ x,
    const float* __restrict__ wt, const float* __restrict__ bt,
    const float* __restrict__ wp, const float* __restrict__ bp,
    const float* __restrict__ wg, const float* __restrict__ bg,
    bf16* __restrict__ qh, bf16* __restrict__ ql,
    bf16* __restrict__ kh, bf16* __restrict__ kl,
    bf16* __restrict__ vv)
{
    const int nt  = blockIdx.x;      // 0..63
    const int pj  = blockIdx.y;      // 0..2
    const int b   = blockIdx.z;      // 0..7
    const int tid = threadIdx.x;
    const int wv  = tid >> 6;
    const int ln  = tid & 63;
    const int lg  = ln >> 4;
    const int lq  = ln & 15;

    const float* W;
    const float* bias;
    if (pj == 0)      { W = wt; bias = bt; }
    else if (pj == 1) { W = wp; bias = bp; }
    else              { W = wg; bias = bg; }
    const bool split = (pj != 2);

    __shared__ char lds[49152];
    char* Ah = lds;            // [64 n][64 c] bf16 hi, swizzled
    char* Al = lds + 8192;
    char* Wh = lds + 16384;    // [128 i][64 c] bf16 hi, swizzled
    char* Wl = lds + 32768;

    f32x4 acc[8];
#pragma unroll
    for (int j = 0; j < 8; ++j) acc[j] = f32x4{0.f, 0.f, 0.f, 0.f};

    const int n0 = nt * 64;

    for (int c0 = 0; c0 < NC; c0 += 64) {
        __syncthreads();
#pragma unroll
        for (int p = 0; p < 4; ++p) {
            int cc = p * 16 + (tid >> 4);
            int nn = (tid & 15) * 4;
            f32x4 xv = *(const f32x4*)(x + ((size_t)b * NC + (c0 + cc)) * NN + n0 + nn);
#pragma unroll
            for (int e = 0; e < 4; ++e) {
                float f = xv[e];
                bf16 h = (bf16)f;
                int row = nn + e;
                int off = (row * 128 + cc * 2) ^ ((row & 7) << 4);
                *(bf16*)(Ah + off) = h;
                *(bf16*)(Al + off) = (bf16)(f - (float)h);
            }
        }
#pragma unroll
        for (int p = 0; p < 8; ++p) {
            int i  = p * 16 + (tid >> 4);
            int c4 = (tid & 15) * 4;
            f32x4 w4 = *(const f32x4*)(W + (size_t)i * NC + c0 + c4);
            bf16x4 hv, lv;
#pragma unroll
            for (int e = 0; e < 4; ++e) {
                bf16 h = (bf16)w4[e];
                hv[e] = h;
                lv[e] = (bf16)(w4[e] - (float)h);
            }
            int off = (i * 128 + c4 * 2) ^ ((i & 7) << 4);
            *(bf16x4*)(Wh + off) = hv;
            if (split) *(bf16x4*)(Wl + off) = lv;
        }
        __syncthreads();
#pragma unroll
        for (int kk = 0; kk < 2; ++kk) {
            int row  = wv * 16 + lq;
            int koff = kk * 64 + lg * 16;
            int aoff = (row * 128 + koff) ^ ((row & 7) << 4);
            bf16x8 ah = *(const bf16x8*)(Ah + aoff);
            bf16x8 al = *(const bf16x8*)(Al + aoff);
#pragma unroll
            for (int j = 0; j < 8; ++j) {
                int ir   = j * 16 + lq;
                int woff = (ir * 128 + koff) ^ ((ir & 7) << 4);
                bf16x8 bh = *(const bf16x8*)(Wh + woff);
                acc[j] = MFMA16(ah, bh, acc[j]);
                if (split) {
                    bf16x8 bl = *(const bf16x8*)(Wl + woff);
                    acc[j] = MFMA16(ah, bl, acc[j]);
                    acc[j] = MFMA16(al, bh, acc[j]);
                }
            }
        }
    }

    if (pj == 2) {
        __syncthreads();
        char* T = lds;   // [128 i][64 n] bf16, swizzled
#pragma unroll
        for (int j = 0; j < 8; ++j) {
            int i = j * 16 + lq;
            float bv = bias[i];
#pragma unroll
            for (int r = 0; r < 4; ++r) {
                int nl = wv * 16 + lg * 4 + r;
                int off = (i * 128 + nl * 2) ^ ((i & 7) << 4);
                *(bf16*)(T + off) = (bf16)(acc[j][r] + bv);
            }
        }
        __syncthreads();
#pragma unroll
        for (int p = 0; p < 4; ++p) {
            int i  = p * 32 + (tid >> 3);
            int sl = tid & 7;
            i32x4 t = *(const i32x4*)(T + ((i * 128 + sl * 16) ^ ((i & 7) << 4)));
            *(i32x4*)(vv + ((size_t)b * NCI + i) * NN + n0 + sl * 8) = t;
        }
    } else {
        const float sc = (pj == 0) ? QSCALE : 1.0f;
#pragma unroll
        for (int j = 0; j < 8; ++j) {
            int i = j * 16 + lq;
            float bv = bias[i];
#pragma unroll
            for (int r = 0; r < 4; ++r) {
                int q = n0 + wv * 16 + lg * 4 + r;
                size_t off = ((size_t)b * NN + q) * NCI + i;
                float val = (acc[j][r] + bv) * sc;
                bf16 h = (bf16)val;
                bf16 l = (bf16)(val - (float)h);
                if (pj == 0) { qh[off] = h; ql[off] = l; }
                else         { kh[off] = h; kl[off] = l; }
            }
        }
    }
}

// ---------------------------------------------------------------------------
// Kernel 2: barrier-free flash attention with KV-split x2.
// 512 blocks x 256 thr (2 blocks/CU via VGPR<=256), 32 q/wave.
// K/V MFMA fragments read directly from global (L2-resident per XCD).
// LDS = per-wave P buffer only. Softmax in exp2 domain, defer-max THR=8.
// ---------------------------------------------------------------------------
__global__ __launch_bounds__(256, 2) void k_attn_sp(
    const bf16* __restrict__ qh, const bf16* __restrict__ ql,
    const bf16* __restrict__ kh, const bf16* __restrict__ kl,
    const bf16* __restrict__ vt,
    bf16* __restrict__ p0, bf16* __restrict__ p1, float* __restrict__ ml)
{
    const int bid = blockIdx.x;       // 0..511
    const int b   = bid & 7;          // batch == XCD (L2 colocation)
    const int rs  = bid >> 3;         // 0..63
    const int qt  = rs & 31;          // 0..31
    const int h   = rs >> 5;          // 0..1
    const int tid = threadIdx.x;
    const int wv  = tid >> 6;
    const int ln  = tid & 63;
    const int lg  = ln >> 4;
    const int lq  = ln & 15;
    const int n0  = qt * 128;
    const int mb0 = h * 2048;
    bf16* ph = h ? p1 : p0;

    __shared__ __attribute__((aligned(16))) char lds[16384];
    char* P = lds + wv * 4096;   // per-wave [32 q][64 m] bf16, swizzled

    // ---- Q fragments (2 q-subtiles x 4 k-chunks), hi/lo, loop-invariant
    bf16x8 qhf[2][4], qlf[2][4];
#pragma unroll
    for (int q2 = 0; q2 < 2; ++q2) {
        int qrow = n0 + wv * 32 + q2 * 16 + lq;
        const bf16* bh = qh + ((size_t)b * NN + qrow) * NCI;
        const bf16* bl = ql + ((size_t)b * NN + qrow) * NCI;
#pragma unroll
        for (int kk = 0; kk < 4; ++kk) {
            qhf[q2][kk] = *(const bf16x8*)(bh + kk * 32 + lg * 8);
            qlf[q2][kk] = *(const bf16x8*)(bl + kk * 32 + lg * 8);
        }
    }

    f32x4 o[2][8];
#pragma unroll
    for (int q2 = 0; q2 < 2; ++q2)
#pragma unroll
        for (int j = 0; j < 8; ++j) o[q2][j] = f32x4{0.f, 0.f, 0.f, 0.f};
    float mrun[2] = {-1e30f, -1e30f};
    float lrun[2] = {0.f, 0.f};

    // per-lane invariant global bases
    const size_t krow0 = ((size_t)b * NN + mb0 + lq) * NCI + lg * 8;
    const bf16* vbase  = vt + ((size_t)b * NCI + lq) * NN + mb0 + lg * 8;

    for (int t = 0; t < 32; ++t) {
        const int m0l = t * 64;   // tile offset within the half

        // ---- swapped QK^T: S^T[m][q], A = K fragments direct from global
        f32x4 s[4][2];
        __builtin_amdgcn_s_setprio(1);
#pragma unroll
        for (int jm = 0; jm < 4; ++jm) {
            const size_t ro = krow0 + (size_t)(m0l + jm * 16) * NCI;
            const bf16* kr = kh + ro;
            const bf16* lr = kl + ro;
            bf16x8 ah[4], al[4];
#pragma unroll
            for (int kk = 0; kk < 4; ++kk) {
                ah[kk] = *(const bf16x8*)(kr + kk * 32);
                al[kk] = *(const bf16x8*)(lr + kk * 32);
            }
            s[jm][0] = f32x4{0.f, 0.f, 0.f, 0.f};
            s[jm][1] = f32x4{0.f, 0.f, 0.f, 0.f};
#pragma unroll
            for (int kk = 0; kk < 4; ++kk) {
                s[jm][0] = MFMA16(ah[kk], qhf[0][kk], s[jm][0]);
                s[jm][1] = MFMA16(ah[kk], qhf[1][kk], s[jm][1]);
                s[jm][0] = MFMA16(al[kk], qhf[0][kk], s[jm][0]);
                s[jm][1] = MFMA16(al[kk], qhf[1][kk], s[jm][1]);
                s[jm][0] = MFMA16(ah[kk], qlf[0][kk], s[jm][0]);
                s[jm][1] = MFMA16(ah[kk], qlf[1][kk], s[jm][1]);
            }
        }
        __builtin_amdgcn_s_setprio(0);

        // ---- online softmax, exp2 domain. Lane owns column q = q2*16+lq.
        float tm[2];
        tm[0] = s[0][0][0];
        tm[1] = s[0][1][0];
#pragma unroll
        for (int jm = 0; jm < 4; ++jm)
#pragma unroll
            for (int r = 0; r < 4; ++r) {
                tm[0] = fmaxf(tm[0], s[jm][0][r]);
                tm[1] = fmaxf(tm[1], s[jm][1][r]);
            }
#pragma unroll
        for (int q2 = 0; q2 < 2; ++q2) {
            tm[q2] = fmaxf(tm[q2], __shfl_xor(tm[q2], 16));
            tm[q2] = fmaxf(tm[q2], __shfl_xor(tm[q2], 32));
        }

        // defer-max: rescale only when the running max grows by > 8 (log2)
        bool grow = (tm[0] > mrun[0] + 8.f) || (tm[1] > mrun[1] + 8.f);
        if (__any(grow)) {
            float alpha[2];
#pragma unroll
            for (int q2 = 0; q2 < 2; ++q2) {
                float mnew = fmaxf(mrun[q2], tm[q2]);
                alpha[q2] = exp2f(mrun[q2] - mnew);
                mrun[q2] = mnew;
                lrun[q2] *= alpha[q2];
            }
            float av0[4], av1[4];
#pragma unroll
            for (int r = 0; r < 4; ++r) {
                av0[r] = __shfl(alpha[0], lg * 4 + r);
                av1[r] = __shfl(alpha[1], lg * 4 + r);
            }
#pragma unroll
            for (int j = 0; j < 8; ++j)
#pragma unroll
                for (int r = 0; r < 4; ++r) {
                    o[0][j][r] *= av0[r];
                    o[1][j][r] *= av1[r];
                }
        }

        // ---- P = exp2(S - m), packed bf16x4 writes to per-wave LDS
        float psum[2] = {0.f, 0.f};
#pragma unroll
        for (int jm = 0; jm < 4; ++jm)
#pragma unroll
            for (int q2 = 0; q2 < 2; ++q2) {
                bf16x4 pk;
#pragma unroll
                for (int r = 0; r < 4; ++r) {
                    float e = exp2f(s[jm][q2][r] - mrun[q2]);
                    psum[q2] += e;
                    pk[r] = (bf16)e;
                }
                int row = q2 * 16 + lq;
                int off = (row * 128 + (jm * 16 + lg * 4) * 2) ^ ((lq & 7) << 4);
                *(bf16x4*)(P + off) = pk;
            }
#pragma unroll
        for (int q2 = 0; q2 < 2; ++q2) {
            psum[q2] += __shfl_xor(psum[q2], 16);
            psum[q2] += __shfl_xor(psum[q2], 32);
            lrun[q2] += psum[q2];
        }

        // ---- PV: O[q][d] += P[q][m] * V[m][d]; V fragments direct from global
        bf16x8 pa[2][2];
#pragma unroll
        for (int q2 = 0; q2 < 2; ++q2)
#pragma unroll
            for (int tt = 0; tt < 2; ++tt) {
                int row = q2 * 16 + lq;
                pa[q2][tt] = *(const bf16x8*)(P + ((row * 128 + tt * 64 + lg * 16) ^ ((lq & 7) << 4)));
            }
        __builtin_amdgcn_s_setprio(1);
#pragma unroll
        for (int j = 0; j < 8; ++j) {
            const bf16* vr = vbase + (size_t)(j * 16) * NN + m0l;
            bf16x8 bv0 = *(const bf16x8*)(vr);
            bf16x8 bv1 = *(const bf16x8*)(vr + 32);
            o[0][j] = MFMA16(pa[0][0], bv0, o[0][j]);
            o[1][j] = MFMA16(pa[1][0], bv0, o[1][j]);
            o[0][j] = MFMA16(pa[0][1], bv1, o[0][j]);
            o[1][j] = MFMA16(pa[1][1], bv1, o[1][j]);
        }
        __builtin_amdgcn_s_setprio(0);
    }

    // ---- epilogue: partial y_h = O / l (bf16), plus (m, l) per row
    float rl0[4], rl1[4];
#pragma unroll
    for (int r = 0; r < 4; ++r) {
        rl0[r] = 1.f / __shfl(lrun[0], lg * 4 + r);
        rl1[r] = 1.f / __shfl(lrun[1], lg * 4 + r);
    }
#pragma unroll
    for (int j = 0; j < 8; ++j) {
        int d = j * 16 + lq;
#pragma unroll
        for (int r = 0; r < 4; ++r) {
            int q0 = n0 + wv * 32 + lg * 4 + r;
            ph[((size_t)b * NN + q0) * NCI + d]      = (bf16)(o[0][j][r] * rl0[r]);
            ph[((size_t)b * NN + q0 + 16) * NCI + d] = (bf16)(o[1][j][r] * rl1[r]);
        }
    }
    if (lg == 0) {
#pragma unroll
        for (int q2 = 0; q2 < 2; ++q2) {
            int row = n0 + wv * 32 + q2 * 16 + lq;
            size_t base = ((size_t)b * NN + row) * 4 + h * 2;
            ml[base]     = mrun[q2];   // log2 domain
            ml[base + 1] = lrun[q2];
        }
    }
}

// ---------------------------------------------------------------------------
// Kernel 2b: combine the two KV-halves (exp2 domain).
// ---------------------------------------------------------------------------
__global__ __launch_bounds__(256) void k_comb(
    const bf16* __restrict__ p0, const bf16* __restrict__ p1,
    const float* __restrict__ ml, bf16* __restrict__ y)
{
    int row = blockIdx.x * 16 + (threadIdx.x >> 4);
    int d0  = (threadIdx.x & 15) * 8;
    f32x4 q = *(const f32x4*)(ml + (size_t)row * 4);  // m0 l0 m1 l1
    float M  = fmaxf(q[0], q[2]);
    float w0 = exp2f(q[0] - M) * q[1];
    float w1 = exp2f(q[2] - M) * q[3];
    float inv = 1.f / (w0 + w1);
    w0 *= inv; w1 *= inv;
    size_t off = (size_t)row * NCI + d0;
    bf16x8 a = *(const bf16x8*)(p0 + off);
    bf16x8 c = *(const bf16x8*)(p1 + off);
    bf16x8 r;
#pragma unroll
    for (int e = 0; e < 8; ++e) r[e] = (bf16)(w0 * (float)a[e] + w1 * (float)c[e]);
    *(bf16x8*)(y + off) = r;
}

// ---------------------------------------------------------------------------
// Kernel 3: out[b,c,n] = x[b,c,n] + sum_i y[b,n,i]*w_out[c,i] + b_out[c]
// ---------------------------------------------------------------------------
__global__ __launch_bounds__(256) void k_out(
    const bf16* __restrict__ y, const float* __restrict__ x,
    const float* __restrict__ w_out, const float* __restrict__ b_out,
    float* __restrict__ out)
{
    const int nt  = blockIdx.x;
    const int b   = blockIdx.y;
    const int tid = threadIdx.x;
    const int wv  = tid >> 6;
    const int ln  = tid & 63;
    const int lg  = ln >> 4;
    const int lq  = ln & 15;
    const int n0  = nt * 64;

    __shared__ char Y[16384];   // [64 n][128 i] bf16, swizzled
#pragma unroll
    for (int p = 0; p < 4; ++p) {
        int nn = p * 16 + (tid >> 4);
        int d0 = (tid & 15) * 8;
        i32x4 t = *(const i32x4*)(y + ((size_t)b * NN + n0 + nn) * NCI + d0);
        *(i32x4*)(Y + ((nn * 256 + d0 * 2) ^ ((nn & 7) << 4))) = t;
    }
    __syncthreads();

    bf16x8 af[4];
    {
        int row = wv * 16 + lq;
#pragma unroll
        for (int kk = 0; kk < 4; ++kk) {
            int koff = kk * 64 + lg * 16;
            af[kk] = *(const bf16x8*)(Y + ((row * 256 + koff) ^ ((row & 7) << 4)));
        }
    }

    f32x4 acc[16];
#pragma unroll
    for (int j = 0; j < 16; ++j) acc[j] = f32x4{0.f, 0.f, 0.f, 0.f};

#pragma unroll
    for (int j = 0; j < 16; ++j) {
        int c = j * 16 + lq;
#pragma unroll
        for (int kk = 0; kk < 4; ++kk) {
            int i0 = kk * 32 + lg * 8;
            f32x4 wa = *(const f32x4*)(w_out + (size_t)c * NCI + i0);
            f32x4 wb = *(const f32x4*)(w_out + (size_t)c * NCI + i0 + 4);
            bf16x8 bw;
#pragma unroll
            for (int e = 0; e < 4; ++e) { bw[e] = (bf16)wa[e]; bw[e + 4] = (bf16)wb[e]; }
            acc[j] = MFMA16(af[kk], bw, acc[j]);
        }
    }

#pragma unroll
    for (int j = 0; j < 16; ++j) {
        int c = j * 16 + lq;
        int nb = n0 + wv * 16 + lg * 4;
        size_t off = ((size_t)b * NC + c) * (size_t)NN + nb;
        f32x4 xv = *(const f32x4*)(x + off);
        float bo = b_out[c];
        f32x4 r;
#pragma unroll
        for (int t = 0; t < 4; ++t) r[t] = acc[j][t] + xv[t] + bo;
        *(f32x4*)(out + off) = r;
    }
}

// ---------------------------------------------------------------------------
extern "C" void kernel_launch(void* const* d_in, const int* in_sizes, int n_in,
                              void* d_out, int out_size, void* d_ws, size_t ws_size,
                              hipStream_t stream)
{
    (void)in_sizes; (void)n_in; (void)out_size; (void)ws_size;
    const float* x  = (const float*)d_in[0];
    const float* wg = (const float*)d_in[1];
    const float* bg = (const float*)d_in[2];
    const float* wt = (const float*)d_in[3];
    const float* bt = (const float*)d_in[4];
    const float* wp = (const float*)d_in[5];
    const float* bp = (const float*)d_in[6];
    const float* wo = (const float*)d_in[7];
    const float* bo = (const float*)d_in[8];
    float* out = (float*)d_out;

    char* ws = (char*)d_ws;
    bf16* qh = (bf16*)(ws);
    bf16* ql = (bf16*)(ws + NEL * 2);
    bf16* kh = (bf16*)(ws + NEL * 4);
    bf16* kl = (bf16*)(ws + NEL * 6);
    bf16* vv = (bf16*)(ws + NEL * 8);    // transposed: [b][ci][n]
    bf16* y  = qh;                       // safe: k_comb writes after qh reads
    bf16* p0 = (bf16*)(ws + NEL * 10);   // KV-split partials
    bf16* p1 = (bf16*)(ws + NEL * 12);
    float* ml = (float*)(ws + NEL * 14); // (ws_size >= 59 MB: proven in R4)

    k_proj<<<dim3(64, 3, 8), 256, 0, stream>>>(x, wt, bt, wp, bp, wg, bg,
                                               qh, ql, kh, kl, vv);
    k_attn_sp<<<dim3(512), 256, 0, stream>>>(qh, ql, kh, kl, vv, p0, p1, ml);
    k_comb<<<dim3(2048), 256, 0, stream>>>(p0, p1, ml, y);
    k_out<<<dim3(64, 8), 256, 0, stream>>>(y, x, wo, bo, out);
}

// Round 6
// 366.623 us; speedup vs baseline: 1.2098x; 1.2098x over previous
//
#include <hip/hip_runtime.h>
#include <hip/hip_bf16.h>
#include <stdint.h>
#include <stddef.h>

// ---------------------------------------------------------------------------
// NonLocalBlock2D: B=8, C=256, H=W=64 (N=4096), CI=128
// out = x + Wout * softmax( (theta(x)^T phi(x)) * sqrt(CI) ) * g(x)
// Split-fp32 (bf16 hi+lo, 3-MFMA) upstream of softmax; plain bf16 after.
// theta pre-scaled by sqrt(128)/ln2 -> softmax in exp2 domain.
// K and V stored in MFMA-FRAGMENT-MAJOR layout so k_attn reads every
// fragment as one coalesced dwordx4 (base + lane*16B) straight from L2.
// k_attn: zero barriers, per-wave P in LDS, KV-split x2 (512 blocks).
// ---------------------------------------------------------------------------

typedef __bf16 bf16;
typedef __attribute__((ext_vector_type(8))) __bf16 bf16x8;
typedef __attribute__((ext_vector_type(4))) __bf16 bf16x4;
typedef __attribute__((ext_vector_type(4))) float  f32x4;
typedef __attribute__((ext_vector_type(4))) int    i32x4;

#define MFMA16(a, b, c) __builtin_amdgcn_mfma_f32_16x16x32_bf16((a), (b), (c), 0, 0, 0)

constexpr int NB  = 8;
constexpr int NC  = 256;
constexpr int NN  = 4096;
constexpr int NCI = 128;
constexpr size_t NEL = (size_t)NB * NN * NCI;
constexpr int PB  = NN * NCI;          // 524288 elems per batch

// sqrt(128) / ln(2): folded into theta so logits are in log2 units.
#define QSCALE (11.313708498984761f * 1.4426950408889634f)

// Fragment layouts (16x16x32 MFMA):
//  Kf[b][m>>4][kk=d>>5][lane][8]  lane = ((d>>3)&3)*16 + (m&15), e = d&7
//  Vf[b][m>>6][j=d>>4][tt=(m&63)>>5][lane][8]
//      lane = ((m>>3)&3)*16 + (d&15), e = m&7

// ---------------------------------------------------------------------------
// Kernel 1: projections.  pj=0 -> theta*QSCALE (std layout, split qh/ql),
// pj=1 -> phi -> fragment-major kh/kl, pj=2 -> g -> fragment-major vv.
// ---------------------------------------------------------------------------
__global__ __launch_bounds__(256) void k_proj(
    const float* __restrict__ x,
    const float* __restrict__ wt, const float* __restrict__ bt,
    const float* __restrict__ wp, const float* __restrict__ bp,
    const float* __restrict__ wg, const float* __restrict__ bg,
    bf16* __restrict__ qh, bf16* __restrict__ ql,
    bf16* __restrict__ kh, bf16* __restrict__ kl,
    bf16* __restrict__ vv)
{
    const int nt  = blockIdx.x;      // 0..63
    const int pj  = blockIdx.y;      // 0..2
    const int b   = blockIdx.z;      // 0..7
    const int tid = threadIdx.x;
    const int wv  = tid >> 6;
    const int ln  = tid & 63;
    const int lg  = ln >> 4;
    const int lq  = ln & 15;

    const float* W;
    const float* bias;
    if (pj == 0)      { W = wt; bias = bt; }
    else if (pj == 1) { W = wp; bias = bp; }
    else              { W = wg; bias = bg; }
    const bool split = (pj != 2);

    __shared__ char lds[49152];
    char* Ah = lds;            // [64 n][64 c] bf16 hi, swizzled
    char* Al = lds + 8192;
    char* Wh = lds + 16384;    // [128 i][64 c] bf16 hi, swizzled
    char* Wl = lds + 32768;

    f32x4 acc[8];
#pragma unroll
    for (int j = 0; j < 8; ++j) acc[j] = f32x4{0.f, 0.f, 0.f, 0.f};

    const int n0 = nt * 64;

    for (int c0 = 0; c0 < NC; c0 += 64) {
        __syncthreads();
#pragma unroll
        for (int p = 0; p < 4; ++p) {
            int cc = p * 16 + (tid >> 4);
            int nn = (tid & 15) * 4;
            f32x4 xv = *(const f32x4*)(x + ((size_t)b * NC + (c0 + cc)) * NN + n0 + nn);
#pragma unroll
            for (int e = 0; e < 4; ++e) {
                float f = xv[e];
                bf16 hh = (bf16)f;
                int row = nn + e;
                int off = (row * 128 + cc * 2) ^ ((row & 7) << 4);
                *(bf16*)(Ah + off) = hh;
                *(bf16*)(Al + off) = (bf16)(f - (float)hh);
            }
        }
#pragma unroll
        for (int p = 0; p < 8; ++p) {
            int i  = p * 16 + (tid >> 4);
            int c4 = (tid & 15) * 4;
            f32x4 w4 = *(const f32x4*)(W + (size_t)i * NC + c0 + c4);
            bf16x4 hv, lv;
#pragma unroll
            for (int e = 0; e < 4; ++e) {
                bf16 hh = (bf16)w4[e];
                hv[e] = hh;
                lv[e] = (bf16)(w4[e] - (float)hh);
            }
            int off = (i * 128 + c4 * 2) ^ ((i & 7) << 4);
            *(bf16x4*)(Wh + off) = hv;
            if (split) *(bf16x4*)(Wl + off) = lv;
        }
        __syncthreads();
#pragma unroll
        for (int kk = 0; kk < 2; ++kk) {
            int row  = wv * 16 + lq;
            int koff = kk * 64 + lg * 16;
            int aoff = (row * 128 + koff) ^ ((row & 7) << 4);
            bf16x8 ah = *(const bf16x8*)(Ah + aoff);
            bf16x8 al = *(const bf16x8*)(Al + aoff);
#pragma unroll
            for (int j = 0; j < 8; ++j) {
                int ir   = j * 16 + lq;
                int woff = (ir * 128 + koff) ^ ((ir & 7) << 4);
                bf16x8 bh = *(const bf16x8*)(Wh + woff);
                acc[j] = MFMA16(ah, bh, acc[j]);
                if (split) {
                    bf16x8 bl = *(const bf16x8*)(Wl + woff);
                    acc[j] = MFMA16(ah, bl, acc[j]);
                    acc[j] = MFMA16(al, bh, acc[j]);
                }
            }
        }
    }

    if (pj == 2) {
        // transpose in LDS, then write V in fragment-major order (16B/lane)
        __syncthreads();
        char* T = lds;   // [128 i][64 n] bf16, swizzled
#pragma unroll
        for (int j = 0; j < 8; ++j) {
            int i = j * 16 + lq;
            float bv2 = bias[i];
#pragma unroll
            for (int r = 0; r < 4; ++r) {
                int nl = wv * 16 + lg * 4 + r;
                int off = (i * 128 + nl * 2) ^ ((i & 7) << 4);
                *(bf16*)(T + off) = (bf16)(acc[j][r] + bv2);
            }
        }
        __syncthreads();
#pragma unroll
        for (int p = 0; p < 4; ++p) {
            int i  = p * 32 + (tid >> 3);   // d channel 0..127
            int sl = tid & 7;               // m'-octet 0..7
            i32x4 tv = *(const i32x4*)(T + ((i * 128 + sl * 16) ^ ((i & 7) << 4)));
            size_t off = (size_t)b * PB
                       + (size_t)((((nt * 8 + (i >> 4)) * 2 + (sl >> 2)) * 64
                                   + (sl & 3) * 16 + (i & 15)) * 8);
            *(i32x4*)(vv + off) = tv;
        }
    } else if (pj == 1) {
        // K: fragment-major scalar stores (hi + lo)
#pragma unroll
        for (int j = 0; j < 8; ++j) {
            int d = j * 16 + lq;
            float bv2 = bias[d];
            const int kkq   = d >> 5;
            const int lpart = ((d >> 3) & 3) * 16;
            const int ee    = d & 7;
#pragma unroll
            for (int r = 0; r < 4; ++r) {
                int m = n0 + wv * 16 + lg * 4 + r;
                float val = acc[j][r] + bv2;
                bf16 hh = (bf16)val;
                bf16 ll = (bf16)(val - (float)hh);
                size_t off = (size_t)b * PB
                           + (size_t)(((m >> 4) * 4 + kkq) * 512
                                      + (lpart + (m & 15)) * 8 + ee);
                kh[off] = hh; kl[off] = ll;
            }
        }
    } else {
        // theta: standard [b][n][ci] layout, QSCALE folded
#pragma unroll
        for (int j = 0; j < 8; ++j) {
            int i = j * 16 + lq;
            float bv2 = bias[i];
#pragma unroll
            for (int r = 0; r < 4; ++r) {
                int q = n0 + wv * 16 + lg * 4 + r;
                size_t off = ((size_t)b * NN + q) * NCI + i;
                float val = (acc[j][r] + bv2) * QSCALE;
                bf16 hh = (bf16)val;
                bf16 ll = (bf16)(val - (float)hh);
                qh[off] = hh; ql[off] = ll;
            }
        }
    }
}

// ---------------------------------------------------------------------------
// Kernel 2: barrier-free flash attention, KV-split x2, coalesced fragment
// loads. 512 blocks x 256 thr (2 blocks/CU), 32 q/wave.
// ---------------------------------------------------------------------------
__global__ __launch_bounds__(256, 1) void k_attn_sp(
    const bf16* __restrict__ qh, const bf16* __restrict__ ql,
    const bf16* __restrict__ kfh, const bf16* __restrict__ kfl,
    const bf16* __restrict__ vf,
    bf16* __restrict__ p0, bf16* __restrict__ p1, float* __restrict__ ml)
{
    const int bid = blockIdx.x;       // 0..511
    const int b   = bid & 7;          // batch == XCD (L2 colocation)
    const int rs  = bid >> 3;         // 0..63
    const int qt  = rs & 31;          // 0..31
    const int h   = rs >> 5;          // 0..1
    const int tid = threadIdx.x;
    const int wv  = tid >> 6;
    const int ln  = tid & 63;
    const int lg  = ln >> 4;
    const int lq  = ln & 15;
    const int n0  = qt * 128;
    bf16* ph = h ? p1 : p0;

    __shared__ __attribute__((aligned(16))) char lds[16384];
    char* P = lds + wv * 4096;   // per-wave [32 q][64 m] bf16, swizzled

    // ---- Q fragments (2 q-subtiles x 4 k-chunks), hi/lo, loop-invariant
    bf16x8 qhf[2][4], qlf[2][4];
#pragma unroll
    for (int q2 = 0; q2 < 2; ++q2) {
        int qrow = n0 + wv * 32 + q2 * 16 + lq;
        const bf16* bh = qh + ((size_t)b * NN + qrow) * NCI;
        const bf16* bl = ql + ((size_t)b * NN + qrow) * NCI;
#pragma unroll
        for (int kk = 0; kk < 4; ++kk) {
            qhf[q2][kk] = *(const bf16x8*)(bh + kk * 32 + lg * 8);
            qlf[q2][kk] = *(const bf16x8*)(bl + kk * 32 + lg * 8);
        }
    }

    f32x4 o[2][8];
#pragma unroll
    for (int q2 = 0; q2 < 2; ++q2)
#pragma unroll
        for (int j = 0; j < 8; ++j) o[q2][j] = f32x4{0.f, 0.f, 0.f, 0.f};
    float mrun[2] = {-1e30f, -1e30f};
    float lrun[2] = {0.f, 0.f};

    // coalesced fragment bases: + lane*16B
    const bf16* kbh = kfh + (size_t)b * PB + (size_t)ln * 8;
    const bf16* kbl = kfl + (size_t)b * PB + (size_t)ln * 8;
    const bf16* vb  = vf  + (size_t)b * PB + (size_t)ln * 8;
    const int mb16 = h * 128;   // (h*2048)>>4
    const int mb64 = h * 32;    // (h*2048)>>6

    for (int t = 0; t < 32; ++t) {
        // ---- swapped QK^T: S^T[m][q], A = K fragments (coalesced from L2)
        f32x4 s[4][2];
        __builtin_amdgcn_s_setprio(1);
#pragma unroll
        for (int jm = 0; jm < 4; ++jm) {
            const size_t kb = (size_t)((mb16 + t * 4 + jm) * 4) * 512;
            bf16x8 ah[4], al[4];
#pragma unroll
            for (int kk = 0; kk < 4; ++kk) {
                ah[kk] = *(const bf16x8*)(kbh + kb + kk * 512);
                al[kk] = *(const bf16x8*)(kbl + kb + kk * 512);
            }
            s[jm][0] = f32x4{0.f, 0.f, 0.f, 0.f};
            s[jm][1] = f32x4{0.f, 0.f, 0.f, 0.f};
#pragma unroll
            for (int kk = 0; kk < 4; ++kk) {
                s[jm][0] = MFMA16(ah[kk], qhf[0][kk], s[jm][0]);
                s[jm][1] = MFMA16(ah[kk], qhf[1][kk], s[jm][1]);
                s[jm][0] = MFMA16(al[kk], qhf[0][kk], s[jm][0]);
                s[jm][1] = MFMA16(al[kk], qhf[1][kk], s[jm][1]);
                s[jm][0] = MFMA16(ah[kk], qlf[0][kk], s[jm][0]);
                s[jm][1] = MFMA16(ah[kk], qlf[1][kk], s[jm][1]);
            }
        }
        __builtin_amdgcn_s_setprio(0);

        // ---- V fragment loads (coalesced; latency hides under softmax)
        bf16x8 bv[8][2];
        {
            const bf16* vp = vb + (size_t)(mb64 + t) * 8192;
#pragma unroll
            for (int j = 0; j < 8; ++j) {
                bv[j][0] = *(const bf16x8*)(vp + (j * 2 + 0) * 512);
                bv[j][1] = *(const bf16x8*)(vp + (j * 2 + 1) * 512);
            }
        }

        // ---- online softmax, exp2 domain. Lane owns column q = q2*16+lq.
        float tm[2];
        tm[0] = s[0][0][0];
        tm[1] = s[0][1][0];
#pragma unroll
        for (int jm = 0; jm < 4; ++jm)
#pragma unroll
            for (int r = 0; r < 4; ++r) {
                tm[0] = fmaxf(tm[0], s[jm][0][r]);
                tm[1] = fmaxf(tm[1], s[jm][1][r]);
            }
#pragma unroll
        for (int q2 = 0; q2 < 2; ++q2) {
            tm[q2] = fmaxf(tm[q2], __shfl_xor(tm[q2], 16));
            tm[q2] = fmaxf(tm[q2], __shfl_xor(tm[q2], 32));
        }

        // defer-max: rescale only when running max grows by > 8 (log2 units)
        bool grow = (tm[0] > mrun[0] + 8.f) || (tm[1] > mrun[1] + 8.f);
        if (__any(grow)) {
            float alpha[2];
#pragma unroll
            for (int q2 = 0; q2 < 2; ++q2) {
                float mnew = fmaxf(mrun[q2], tm[q2]);
                alpha[q2] = exp2f(mrun[q2] - mnew);
                mrun[q2] = mnew;
                lrun[q2] *= alpha[q2];
            }
            float av0[4], av1[4];
#pragma unroll
            for (int r = 0; r < 4; ++r) {
                av0[r] = __shfl(alpha[0], lg * 4 + r);
                av1[r] = __shfl(alpha[1], lg * 4 + r);
            }
#pragma unroll
            for (int j = 0; j < 8; ++j)
#pragma unroll
                for (int r = 0; r < 4; ++r) {
                    o[0][j][r] *= av0[r];
                    o[1][j][r] *= av1[r];
                }
        }

        // ---- P = exp2(S - m), packed bf16x4 writes to per-wave LDS
        float psum[2] = {0.f, 0.f};
#pragma unroll
        for (int jm = 0; jm < 4; ++jm)
#pragma unroll
            for (int q2 = 0; q2 < 2; ++q2) {
                bf16x4 pk;
#pragma unroll
                for (int r = 0; r < 4; ++r) {
                    float e2 = exp2f(s[jm][q2][r] - mrun[q2]);
                    psum[q2] += e2;
                    pk[r] = (bf16)e2;
                }
                int row = q2 * 16 + lq;
                int off = (row * 128 + (jm * 16 + lg * 4) * 2) ^ ((lq & 7) << 4);
                *(bf16x4*)(P + off) = pk;
            }
#pragma unroll
        for (int q2 = 0; q2 < 2; ++q2) {
            psum[q2] += __shfl_xor(psum[q2], 16);
            psum[q2] += __shfl_xor(psum[q2], 32);
            lrun[q2] += psum[q2];
        }

        // ---- PV: O[q][d] += P[q][m] * V[m][d]
        bf16x8 pa[2][2];
#pragma unroll
        for (int q2 = 0; q2 < 2; ++q2)
#pragma unroll
            for (int tt = 0; tt < 2; ++tt) {
                int row = q2 * 16 + lq;
                pa[q2][tt] = *(const bf16x8*)(P + ((row * 128 + tt * 64 + lg * 16) ^ ((lq & 7) << 4)));
            }
        __builtin_amdgcn_s_setprio(1);
#pragma unroll
        for (int j = 0; j < 8; ++j) {
            o[0][j] = MFMA16(pa[0][0], bv[j][0], o[0][j]);
            o[1][j] = MFMA16(pa[1][0], bv[j][0], o[1][j]);
            o[0][j] = MFMA16(pa[0][1], bv[j][1], o[0][j]);
            o[1][j] = MFMA16(pa[1][1], bv[j][1], o[1][j]);
        }
        __builtin_amdgcn_s_setprio(0);
    }

    // ---- epilogue: partial y_h = O / l (bf16), plus (m, l) per row
    float rl0[4], rl1[4];
#pragma unroll
    for (int r = 0; r < 4; ++r) {
        rl0[r] = 1.f / __shfl(lrun[0], lg * 4 + r);
        rl1[r] = 1.f / __shfl(lrun[1], lg * 4 + r);
    }
#pragma unroll
    for (int j = 0; j < 8; ++j) {
        int d = j * 16 + lq;
#pragma unroll
        for (int r = 0; r < 4; ++r) {
            int q0 = n0 + wv * 32 + lg * 4 + r;
            ph[((size_t)b * NN + q0) * NCI + d]      = (bf16)(o[0][j][r] * rl0[r]);
            ph[((size_t)b * NN + q0 + 16) * NCI + d] = (bf16)(o[1][j][r] * rl1[r]);
        }
    }
    if (lg == 0) {
#pragma unroll
        for (int q2 = 0; q2 < 2; ++q2) {
            int row = n0 + wv * 32 + q2 * 16 + lq;
            size_t base = ((size_t)b * NN + row) * 4 + h * 2;
            ml[base]     = mrun[q2];   // log2 domain
            ml[base + 1] = lrun[q2];
        }
    }
}

// ---------------------------------------------------------------------------
// Kernel 2b: combine the two KV-halves (exp2 domain).
// ---------------------------------------------------------------------------
__global__ __launch_bounds__(256) void k_comb(
    const bf16* __restrict__ p0, const bf16* __restrict__ p1,
    const float* __restrict__ ml, bf16* __restrict__ y)
{
    int row = blockIdx.x * 16 + (threadIdx.x >> 4);
    int d0  = (threadIdx.x & 15) * 8;
    f32x4 q = *(const f32x4*)(ml + (size_t)row * 4);  // m0 l0 m1 l1
    float M  = fmaxf(q[0], q[2]);
    float w0 = exp2f(q[0] - M) * q[1];
    float w1 = exp2f(q[2] - M) * q[3];
    float inv = 1.f / (w0 + w1);
    w0 *= inv; w1 *= inv;
    size_t off = (size_t)row * NCI + d0;
    bf16x8 a = *(const bf16x8*)(p0 + off);
    bf16x8 c = *(const bf16x8*)(p1 + off);
    bf16x8 r;
#pragma unroll
    for (int e = 0; e < 8; ++e) r[e] = (bf16)(w0 * (float)a[e] + w1 * (float)c[e]);
    *(bf16x8*)(y + off) = r;
}

// ---------------------------------------------------------------------------
// Kernel 3: out[b,c,n] = x[b,c,n] + sum_i y[b,n,i]*w_out[c,i] + b_out[c]
// ---------------------------------------------------------------------------
__global__ __launch_bounds__(256) void k_out(
    const bf16* __restrict__ y, const float* __restrict__ x,
    const float* __restrict__ w_out, const float* __restrict__ b_out,
    float* __restrict__ out)
{
    const int nt  = blockIdx.x;
    const int b   = blockIdx.y;
    const int tid = threadIdx.x;
    const int wv  = tid >> 6;
    const int ln  = tid & 63;
    const int lg  = ln >> 4;
    const int lq  = ln & 15;
    const int n0  = nt * 64;

    __shared__ char Y[16384];   // [64 n][128 i] bf16, swizzled
#pragma unroll
    for (int p = 0; p < 4; ++p) {
        int nn = p * 16 + (tid >> 4);
        int d0 = (tid & 15) * 8;
        i32x4 t = *(const i32x4*)(y + ((size_t)b * NN + n0 + nn) * NCI + d0);
        *(i32x4*)(Y + ((nn * 256 + d0 * 2) ^ ((nn & 7) << 4))) = t;
    }
    __syncthreads();

    bf16x8 af[4];
    {
        int row = wv * 16 + lq;
#pragma unroll
        for (int kk = 0; kk < 4; ++kk) {
            int koff = kk * 64 + lg * 16;
            af[kk] = *(const bf16x8*)(Y + ((row * 256 + koff) ^ ((row & 7) << 4)));
        }
    }

    f32x4 acc[16];
#pragma unroll
    for (int j = 0; j < 16; ++j) acc[j] = f32x4{0.f, 0.f, 0.f, 0.f};

#pragma unroll
    for (int j = 0; j < 16; ++j) {
        int c = j * 16 + lq;
#pragma unroll
        for (int kk = 0; kk < 4; ++kk) {
            int i0 = kk * 32 + lg * 8;
            f32x4 wa = *(const f32x4*)(w_out + (size_t)c * NCI + i0);
            f32x4 wb = *(const f32x4*)(w_out + (size_t)c * NCI + i0 + 4);
            bf16x8 bw;
#pragma unroll
            for (int e = 0; e < 4; ++e) { bw[e] = (bf16)wa[e]; bw[e + 4] = (bf16)wb[e]; }
            acc[j] = MFMA16(af[kk], bw, acc[j]);
        }
    }

#pragma unroll
    for (int j = 0; j < 16; ++j) {
        int c = j * 16 + lq;
        int nb = n0 + wv * 16 + lg * 4;
        size_t off = ((size_t)b * NC + c) * (size_t)NN + nb;
        f32x4 xv = *(const f32x4*)(x + off);
        float bo = b_out[c];
        f32x4 r;
#pragma unroll
        for (int t = 0; t < 4; ++t) r[t] = acc[j][t] + xv[t] + bo;
        *(f32x4*)(out + off) = r;
    }
}

// ---------------------------------------------------------------------------
extern "C" void kernel_launch(void* const* d_in, const int* in_sizes, int n_in,
                              void* d_out, int out_size, void* d_ws, size_t ws_size,
                              hipStream_t stream)
{
    (void)in_sizes; (void)n_in; (void)out_size; (void)ws_size;
    const float* x  = (const float*)d_in[0];
    const float* wg = (const float*)d_in[1];
    const float* bg = (const float*)d_in[2];
    const float* wt = (const float*)d_in[3];
    const float* bt = (const float*)d_in[4];
    const float* wp = (const float*)d_in[5];
    const float* bp = (const float*)d_in[6];
    const float* wo = (const float*)d_in[7];
    const float* bo = (const float*)d_in[8];
    float* out = (float*)d_out;

    char* ws = (char*)d_ws;
    bf16* qh = (bf16*)(ws);
    bf16* ql = (bf16*)(ws + NEL * 2);
    bf16* kh = (bf16*)(ws + NEL * 4);    // fragment-major K hi
    bf16* kl = (bf16*)(ws + NEL * 6);    // fragment-major K lo
    bf16* vv = (bf16*)(ws + NEL * 8);    // fragment-major V
    bf16* y  = qh;                       // safe: k_comb writes after qh reads
    bf16* p0 = (bf16*)(ws + NEL * 10);   // KV-split partials
    bf16* p1 = (bf16*)(ws + NEL * 12);
    float* ml = (float*)(ws + NEL * 14); // (ws_size >= 59 MB: proven in R4)

    k_proj<<<dim3(64, 3, 8), 256, 0, stream>>>(x, wt, bt, wp, bp, wg, bg,
                                               qh, ql, kh, kl, vv);
    k_attn_sp<<<dim3(512), 256, 0, stream>>>(qh, ql, kh, kl, vv, p0, p1, ml);
    k_comb<<<dim3(2048), 256, 0, stream>>>(p0, p1, ml, y);
    k_out<<<dim3(64, 8), 256, 0, stream>>>(y, x, wo, bo, out);
}

// Round 7
// 264.516 us; speedup vs baseline: 1.6768x; 1.3860x over previous
//
#include <hip/hip_runtime.h>
#include <hip/hip_bf16.h>
#include <stdint.h>
#include <stddef.h>

// ---------------------------------------------------------------------------
// NonLocalBlock2D: B=8, C=256, H=W=64 (N=4096), CI=128
// out = x + Wout * softmax( (theta(x)^T phi(x)) * sqrt(CI) ) * g(x)
// Split-fp32 (bf16 hi+lo, 3-MFMA) upstream of softmax; plain bf16 after.
// theta pre-scaled by sqrt(128)/ln2 -> softmax in exp2 domain.
// K stored standard [b][m][d] (hi/lo) and staged in LDS (R2 structure);
// V stored fragment-major so PV reads it as coalesced dwordx4 from L2.
// k_attn: 512 blocks x 256 thr (2 blocks/CU), 4 waves x 16 q, BK=64,
// 2 barriers/iter, defer-max online softmax.
// ---------------------------------------------------------------------------

typedef __bf16 bf16;
typedef __attribute__((ext_vector_type(8))) __bf16 bf16x8;
typedef __attribute__((ext_vector_type(4))) __bf16 bf16x4;
typedef __attribute__((ext_vector_type(4))) float  f32x4;
typedef __attribute__((ext_vector_type(4))) int    i32x4;

#define MFMA16(a, b, c) __builtin_amdgcn_mfma_f32_16x16x32_bf16((a), (b), (c), 0, 0, 0)

constexpr int NB  = 8;
constexpr int NC  = 256;
constexpr int NN  = 4096;
constexpr int NCI = 128;
constexpr size_t NEL = (size_t)NB * NN * NCI;
constexpr int PBATCH = NN * NCI;       // elems per batch

// sqrt(128) / ln(2): folded into theta so logits are in log2 units.
#define QSCALE (11.313708498984761f * 1.4426950408889634f)

// V fragment layout (16x16x32 MFMA B-operand):
//  Vf[b][m>>6][j=d>>4][tt=(m&63)>>5][lane][8], lane=((m>>3)&3)*16+(d&15), e=m&7

// ---------------------------------------------------------------------------
// Kernel 1: projections.  pj=0 -> theta*QSCALE (std, split qh/ql),
// pj=1 -> phi (std, split kh/kl), pj=2 -> g -> fragment-major vv.
// ---------------------------------------------------------------------------
__global__ __launch_bounds__(256) void k_proj(
    const float* __restrict__ x,
    const float* __restrict__ wt, const float* __restrict__ bt,
    const float* __restrict__ wp, const float* __restrict__ bp,
    const float* __restrict__ wg, const float* __restrict__ bg,
    bf16* __restrict__ qh, bf16* __restrict__ ql,
    bf16* __restrict__ kh, bf16* __restrict__ kl,
    bf16* __restrict__ vv)
{
    const int nt  = blockIdx.x;      // 0..63
    const int pj  = blockIdx.y;      // 0..2
    const int b   = blockIdx.z;      // 0..7
    const int tid = threadIdx.x;
    const int wv  = tid >> 6;
    const int ln  = tid & 63;
    const int lg  = ln >> 4;
    const int lq  = ln & 15;

    const float* W;
    const float* bias;
    if (pj == 0)      { W = wt; bias = bt; }
    else if (pj == 1) { W = wp; bias = bp; }
    else              { W = wg; bias = bg; }
    const bool split = (pj != 2);

    __shared__ char lds[49152];
    char* Ah = lds;            // [64 n][64 c] bf16 hi, swizzled
    char* Al = lds + 8192;
    char* Wh = lds + 16384;    // [128 i][64 c] bf16 hi, swizzled
    char* Wl = lds + 32768;

    f32x4 acc[8];
#pragma unroll
    for (int j = 0; j < 8; ++j) acc[j] = f32x4{0.f, 0.f, 0.f, 0.f};

    const int n0 = nt * 64;

    for (int c0 = 0; c0 < NC; c0 += 64) {
        __syncthreads();
#pragma unroll
        for (int p = 0; p < 4; ++p) {
            int cc = p * 16 + (tid >> 4);
            int nn = (tid & 15) * 4;
            f32x4 xv = *(const f32x4*)(x + ((size_t)b * NC + (c0 + cc)) * NN + n0 + nn);
#pragma unroll
            for (int e = 0; e < 4; ++e) {
                float f = xv[e];
                bf16 hh = (bf16)f;
                int row = nn + e;
                int off = (row * 128 + cc * 2) ^ ((row & 7) << 4);
                *(bf16*)(Ah + off) = hh;
                *(bf16*)(Al + off) = (bf16)(f - (float)hh);
            }
        }
#pragma unroll
        for (int p = 0; p < 8; ++p) {
            int i  = p * 16 + (tid >> 4);
            int c4 = (tid & 15) * 4;
            f32x4 w4 = *(const f32x4*)(W + (size_t)i * NC + c0 + c4);
            bf16x4 hv, lv;
#pragma unroll
            for (int e = 0; e < 4; ++e) {
                bf16 hh = (bf16)w4[e];
                hv[e] = hh;
                lv[e] = (bf16)(w4[e] - (float)hh);
            }
            int off = (i * 128 + c4 * 2) ^ ((i & 7) << 4);
            *(bf16x4*)(Wh + off) = hv;
            if (split) *(bf16x4*)(Wl + off) = lv;
        }
        __syncthreads();
#pragma unroll
        for (int kk = 0; kk < 2; ++kk) {
            int row  = wv * 16 + lq;
            int koff = kk * 64 + lg * 16;
            int aoff = (row * 128 + koff) ^ ((row & 7) << 4);
            bf16x8 ah = *(const bf16x8*)(Ah + aoff);
            bf16x8 al = *(const bf16x8*)(Al + aoff);
#pragma unroll
            for (int j = 0; j < 8; ++j) {
                int ir   = j * 16 + lq;
                int woff = (ir * 128 + koff) ^ ((ir & 7) << 4);
                bf16x8 bh = *(const bf16x8*)(Wh + woff);
                acc[j] = MFMA16(ah, bh, acc[j]);
                if (split) {
                    bf16x8 bl = *(const bf16x8*)(Wl + woff);
                    acc[j] = MFMA16(ah, bl, acc[j]);
                    acc[j] = MFMA16(al, bh, acc[j]);
                }
            }
        }
    }

    if (pj == 2) {
        // transpose in LDS, then write V fragment-major (16B/lane, coalesced)
        __syncthreads();
        char* T = lds;   // [128 i][64 n] bf16, swizzled
#pragma unroll
        for (int j = 0; j < 8; ++j) {
            int i = j * 16 + lq;
            float bv2 = bias[i];
#pragma unroll
            for (int r = 0; r < 4; ++r) {
                int nl = wv * 16 + lg * 4 + r;
                int off = (i * 128 + nl * 2) ^ ((i & 7) << 4);
                *(bf16*)(T + off) = (bf16)(acc[j][r] + bv2);
            }
        }
        __syncthreads();
#pragma unroll
        for (int p = 0; p < 4; ++p) {
            int i  = p * 32 + (tid >> 3);   // d channel 0..127
            int sl = tid & 7;               // m-octet 0..7
            i32x4 tv = *(const i32x4*)(T + ((i * 128 + sl * 16) ^ ((i & 7) << 4)));
            size_t off = (size_t)b * PBATCH
                       + (size_t)((((nt * 8 + (i >> 4)) * 2 + (sl >> 2)) * 64
                                   + (sl & 3) * 16 + (i & 15)) * 8);
            *(i32x4*)(vv + off) = tv;
        }
    } else {
        const float sc = (pj == 0) ? QSCALE : 1.0f;
#pragma unroll
        for (int j = 0; j < 8; ++j) {
            int i = j * 16 + lq;
            float bv2 = bias[i];
#pragma unroll
            for (int r = 0; r < 4; ++r) {
                int q = n0 + wv * 16 + lg * 4 + r;
                size_t off = ((size_t)b * NN + q) * NCI + i;
                float val = (acc[j][r] + bv2) * sc;
                bf16 hh = (bf16)val;
                bf16 ll = (bf16)(val - (float)hh);
                if (pj == 0) { qh[off] = hh; ql[off] = ll; }
                else         { kh[off] = hh; kl[off] = ll; }
            }
        }
    }
}

// ---------------------------------------------------------------------------
// Kernel 2: flash attention (R2 structure + V-direct + exp2/defer-max).
// 512 blocks x 256 thr (2 blocks/CU), 4 waves x 16 q, BK=64, 2 barriers/iter.
// ---------------------------------------------------------------------------
__global__ __launch_bounds__(256, 2) void k_attn(
    const bf16* __restrict__ qh, const bf16* __restrict__ ql,
    const bf16* __restrict__ kh, const bf16* __restrict__ kl,
    const bf16* __restrict__ vf, bf16* __restrict__ y)
{
    const int bid = blockIdx.x;       // 0..511
    const int b   = bid & 7;          // batch == XCD (L2 colocation)
    const int qt  = bid >> 3;         // 0..63
    const int tid = threadIdx.x;
    const int wv  = tid >> 6;
    const int ln  = tid & 63;
    const int lg  = ln >> 4;          // 0..3
    const int lq  = ln & 15;
    const int n0  = qt * 64;

    // LDS: KH 16K, KL 16K, P 4x2K  -> 40 KB (2 blocks/CU)
    __shared__ __attribute__((aligned(16))) char lds[40960];
    char* KH = lds;
    char* KL = lds + 16384;
    char* P  = lds + 32768 + wv * 2048;   // per-wave [16 q][64 m] bf16, swizzled

    // ---- Q fragments (loop-invariant). B-frag: col=lq=q, k=lg*8+e.
    bf16x8 qhf[4], qlf[4];
    {
        int qrow = n0 + wv * 16 + lq;
        const bf16* bh = qh + ((size_t)b * NN + qrow) * NCI;
        const bf16* bl = ql + ((size_t)b * NN + qrow) * NCI;
#pragma unroll
        for (int kk = 0; kk < 4; ++kk) {
            int d0 = kk * 32 + lg * 8;
            qhf[kk] = *(const bf16x8*)(bh + d0);
            qlf[kk] = *(const bf16x8*)(bl + d0);
        }
    }

    f32x4 o[8];
#pragma unroll
    for (int j = 0; j < 8; ++j) o[j] = f32x4{0.f, 0.f, 0.f, 0.f};
    float mrun = -1e30f, lrun = 0.f;

    // V fragment-major base: + lane*16B (coalesced)
    const bf16* vb = vf + (size_t)b * PBATCH + (size_t)ln * 8;

    for (int m0 = 0; m0 < NN; m0 += 64) {
        __syncthreads();   // (A) previous K tile fully consumed
        // ---- stage K hi/lo into LDS (direct global->reg->LDS, R2 style)
#pragma unroll
        for (int p = 0; p < 4; ++p) {
            int mm = p * 16 + (tid >> 4);
            int sl = tid & 15;
            size_t g = ((size_t)b * NN + m0 + mm) * NCI + sl * 8;
            int off = (mm * 256 + sl * 16) ^ ((mm & 7) << 4);
            *(i32x4*)(KH + off) = *(const i32x4*)(kh + g);
            *(i32x4*)(KL + off) = *(const i32x4*)(kl + g);
        }
        __syncthreads();   // (B) staging visible

        // ---- issue V fragment loads now; latency hides under QK^T+softmax
        bf16x8 bv[8][2];
        {
            const bf16* vp = vb + (size_t)(m0 >> 6) * 8192;
#pragma unroll
            for (int j = 0; j < 8; ++j) {
                bv[j][0] = *(const bf16x8*)(vp + (j * 2 + 0) * 512);
                bv[j][1] = *(const bf16x8*)(vp + (j * 2 + 1) * 512);
            }
        }

        // ---- swapped QK^T: S^T[m][q], A=K (LDS), B=Q (regs), split 3-MFMA
        f32x4 s[4];
        __builtin_amdgcn_s_setprio(1);
#pragma unroll
        for (int jm = 0; jm < 4; ++jm) {
            s[jm] = f32x4{0.f, 0.f, 0.f, 0.f};
            const int mrow = jm * 16 + lq;
            const int sw = (mrow & 7) << 4;
#pragma unroll
            for (int kk = 0; kk < 4; ++kk) {
                int aoff = (mrow * 256 + kk * 64 + lg * 16) ^ sw;
                bf16x8 ah = *(const bf16x8*)(KH + aoff);
                bf16x8 al = *(const bf16x8*)(KL + aoff);
                s[jm] = MFMA16(ah, qhf[kk], s[jm]);
                s[jm] = MFMA16(al, qhf[kk], s[jm]);
                s[jm] = MFMA16(ah, qlf[kk], s[jm]);
            }
        }
        __builtin_amdgcn_s_setprio(0);

        // ---- online softmax (exp2 domain). Lane owns column q = lq.
        float tm = s[0][0];
#pragma unroll
        for (int jm = 0; jm < 4; ++jm)
#pragma unroll
            for (int r = 0; r < 4; ++r) tm = fmaxf(tm, s[jm][r]);
        tm = fmaxf(tm, __shfl_xor(tm, 16));
        tm = fmaxf(tm, __shfl_xor(tm, 32));

        // defer-max: rescale only when running max grows by > 8 (log2 units)
        if (__any(tm > mrun + 8.f)) {
            float mnew = fmaxf(mrun, tm);
            float alpha = exp2f(mrun - mnew);
            mrun = mnew;
            lrun *= alpha;
            float av[4];
#pragma unroll
            for (int r = 0; r < 4; ++r) av[r] = __shfl(alpha, lg * 4 + r);
#pragma unroll
            for (int j = 0; j < 8; ++j)
#pragma unroll
                for (int r = 0; r < 4; ++r) o[j][r] *= av[r];
        }

        // ---- P = exp2(S - m), packed bf16x4 writes to per-wave LDS
        float psum = 0.f;
#pragma unroll
        for (int jm = 0; jm < 4; ++jm) {
            bf16x4 pk;
#pragma unroll
            for (int r = 0; r < 4; ++r) {
                float e2 = exp2f(s[jm][r] - mrun);
                psum += e2;
                pk[r] = (bf16)e2;
            }
            int off = (lq * 128 + (jm * 16 + lg * 4) * 2) ^ ((lq & 7) << 4);
            *(bf16x4*)(P + off) = pk;
        }
        psum += __shfl_xor(psum, 16);
        psum += __shfl_xor(psum, 32);
        lrun += psum;

        // ---- PV: O[q][d] += P[q][m] * V[m][d]; A=P (LDS), B=V (regs, L2)
        bf16x8 pa[2];
#pragma unroll
        for (int tt = 0; tt < 2; ++tt)
            pa[tt] = *(const bf16x8*)(P + ((lq * 128 + tt * 64 + lg * 16) ^ ((lq & 7) << 4)));
        __builtin_amdgcn_s_setprio(1);
#pragma unroll
        for (int j = 0; j < 8; ++j) {
            o[j] = MFMA16(pa[0], bv[j][0], o[j]);
            o[j] = MFMA16(pa[1], bv[j][1], o[j]);
        }
        __builtin_amdgcn_s_setprio(0);
    }

    // ---- epilogue: y = O / l
    float rl[4];
#pragma unroll
    for (int r = 0; r < 4; ++r) rl[r] = 1.f / __shfl(lrun, lg * 4 + r);
#pragma unroll
    for (int j = 0; j < 8; ++j) {
        int d = j * 16 + lq;
#pragma unroll
        for (int r = 0; r < 4; ++r) {
            int q = n0 + wv * 16 + lg * 4 + r;
            y[((size_t)b * NN + q) * NCI + d] = (bf16)(o[j][r] * rl[r]);
        }
    }
}

// ---------------------------------------------------------------------------
// Kernel 3: out[b,c,n] = x[b,c,n] + sum_i y[b,n,i]*w_out[c,i] + b_out[c]
// ---------------------------------------------------------------------------
__global__ __launch_bounds__(256) void k_out(
    const bf16* __restrict__ y, const float* __restrict__ x,
    const float* __restrict__ w_out, const float* __restrict__ b_out,
    float* __restrict__ out)
{
    const int nt  = blockIdx.x;
    const int b   = blockIdx.y;
    const int tid = threadIdx.x;
    const int wv  = tid >> 6;
    const int ln  = tid & 63;
    const int lg  = ln >> 4;
    const int lq  = ln & 15;
    const int n0  = nt * 64;

    __shared__ char Y[16384];   // [64 n][128 i] bf16, swizzled
#pragma unroll
    for (int p = 0; p < 4; ++p) {
        int nn = p * 16 + (tid >> 4);
        int d0 = (tid & 15) * 8;
        i32x4 t = *(const i32x4*)(y + ((size_t)b * NN + n0 + nn) * NCI + d0);
        *(i32x4*)(Y + ((nn * 256 + d0 * 2) ^ ((nn & 7) << 4))) = t;
    }
    __syncthreads();

    bf16x8 af[4];
    {
        int row = wv * 16 + lq;
#pragma unroll
        for (int kk = 0; kk < 4; ++kk) {
            int koff = kk * 64 + lg * 16;
            af[kk] = *(const bf16x8*)(Y + ((row * 256 + koff) ^ ((row & 7) << 4)));
        }
    }

    f32x4 acc[16];
#pragma unroll
    for (int j = 0; j < 16; ++j) acc[j] = f32x4{0.f, 0.f, 0.f, 0.f};

#pragma unroll
    for (int j = 0; j < 16; ++j) {
        int c = j * 16 + lq;
#pragma unroll
        for (int kk = 0; kk < 4; ++kk) {
            int i0 = kk * 32 + lg * 8;
            f32x4 wa = *(const f32x4*)(w_out + (size_t)c * NCI + i0);
            f32x4 wb = *(const f32x4*)(w_out + (size_t)c * NCI + i0 + 4);
            bf16x8 bw;
#pragma unroll
            for (int e = 0; e < 4; ++e) { bw[e] = (bf16)wa[e]; bw[e + 4] = (bf16)wb[e]; }
            acc[j] = MFMA16(af[kk], bw, acc[j]);
        }
    }

#pragma unroll
    for (int j = 0; j < 16; ++j) {
        int c = j * 16 + lq;
        int nb = n0 + wv * 16 + lg * 4;
        size_t off = ((size_t)b * NC + c) * (size_t)NN + nb;
        f32x4 xv = *(const f32x4*)(x + off);
        float bo = b_out[c];
        f32x4 r;
#pragma unroll
        for (int t = 0; t < 4; ++t) r[t] = acc[j][t] + xv[t] + bo;
        *(f32x4*)(out + off) = r;
    }
}

// ---------------------------------------------------------------------------
extern "C" void kernel_launch(void* const* d_in, const int* in_sizes, int n_in,
                              void* d_out, int out_size, void* d_ws, size_t ws_size,
                              hipStream_t stream)
{
    (void)in_sizes; (void)n_in; (void)out_size; (void)ws_size;
    const float* x  = (const float*)d_in[0];
    const float* wg = (const float*)d_in[1];
    const float* bg = (const float*)d_in[2];
    const float* wt = (const float*)d_in[3];
    const float* bt = (const float*)d_in[4];
    const float* wp = (const float*)d_in[5];
    const float* bp = (const float*)d_in[6];
    const float* wo = (const float*)d_in[7];
    const float* bo = (const float*)d_in[8];
    float* out = (float*)d_out;

    char* ws = (char*)d_ws;
    bf16* qh = (bf16*)(ws);
    bf16* ql = (bf16*)(ws + NEL * 2);
    bf16* kh = (bf16*)(ws + NEL * 4);    // standard [b][m][d] hi
    bf16* kl = (bf16*)(ws + NEL * 6);    // standard [b][m][d] lo
    bf16* vv = (bf16*)(ws + NEL * 8);    // fragment-major V
    bf16* y  = qh;   // safe: k_attn reads its own Q rows before writing them

    k_proj<<<dim3(64, 3, 8), 256, 0, stream>>>(x, wt, bt, wp, bp, wg, bg,
                                               qh, ql, kh, kl, vv);
    k_attn<<<dim3(512), 256, 0, stream>>>(qh, ql, kh, kl, vv, y);
    k_out<<<dim3(64, 8), 256, 0, stream>>>(y, x, wo, bo, out);
}

// Round 8
// 255.144 us; speedup vs baseline: 1.7384x; 1.0367x over previous
//
#include <hip/hip_runtime.h>
#include <hip/hip_bf16.h>
#include <stdint.h>
#include <stddef.h>

// ---------------------------------------------------------------------------
// NonLocalBlock2D: B=8, C=256, H=W=64 (N=4096), CI=128
// out = x + Wout * softmax( (theta(x)^T phi(x)) * sqrt(CI) ) * g(x)
// Split-fp32 (bf16 hi+lo, 3-MFMA) upstream of softmax; plain bf16 after.
// theta pre-scaled by sqrt(128)/ln2 -> softmax in exp2 domain.
// K standard [b][m][d] hi/lo staged via double-buffered LDS (reg prefetch,
// 1 barrier/iter); V fragment-major, read as coalesced dwordx4 from L2 with
// sched_barrier-pinned early issue.
// ---------------------------------------------------------------------------

typedef __bf16 bf16;
typedef __attribute__((ext_vector_type(8))) __bf16 bf16x8;
typedef __attribute__((ext_vector_type(4))) __bf16 bf16x4;
typedef __attribute__((ext_vector_type(4))) float  f32x4;
typedef __attribute__((ext_vector_type(4))) int    i32x4;

#define MFMA16(a, b, c) __builtin_amdgcn_mfma_f32_16x16x32_bf16((a), (b), (c), 0, 0, 0)

constexpr int NB  = 8;
constexpr int NC  = 256;
constexpr int NN  = 4096;
constexpr int NCI = 128;
constexpr size_t NEL = (size_t)NB * NN * NCI;
constexpr int PBATCH = NN * NCI;       // elems per batch

// sqrt(128) / ln(2): folded into theta so logits are in log2 units.
#define QSCALE (11.313708498984761f * 1.4426950408889634f)

// V fragment layout (16x16x32 MFMA B-operand):
//  Vf[b][m>>6][j=d>>4][tt=(m&63)>>5][lane][8], lane=((m>>3)&3)*16+(d&15), e=m&7

// ---------------------------------------------------------------------------
// Kernel 1: projections.  pj=0 -> theta*QSCALE (std, split qh/ql),
// pj=1 -> phi (std, split kh/kl), pj=2 -> g -> fragment-major vv.
// ---------------------------------------------------------------------------
__global__ __launch_bounds__(256) void k_proj(
    const float* __restrict__ x,
    const float* __restrict__ wt, const float* __restrict__ bt,
    const float* __restrict__ wp, const float* __restrict__ bp,
    const float* __restrict__ wg, const float* __restrict__ bg,
    bf16* __restrict__ qh, bf16* __restrict__ ql,
    bf16* __restrict__ kh, bf16* __restrict__ kl,
    bf16* __restrict__ vv)
{
    const int nt  = blockIdx.x;      // 0..63
    const int pj  = blockIdx.y;      // 0..2
    const int b   = blockIdx.z;      // 0..7
    const int tid = threadIdx.x;
    const int wv  = tid >> 6;
    const int ln  = tid & 63;
    const int lg  = ln >> 4;
    const int lq  = ln & 15;

    const float* W;
    const float* bias;
    if (pj == 0)      { W = wt; bias = bt; }
    else if (pj == 1) { W = wp; bias = bp; }
    else              { W = wg; bias = bg; }
    const bool split = (pj != 2);

    __shared__ char lds[49152];
    char* Ah = lds;            // [64 n][64 c] bf16 hi, swizzled
    char* Al = lds + 8192;
    char* Wh = lds + 16384;    // [128 i][64 c] bf16 hi, swizzled
    char* Wl = lds + 32768;

    f32x4 acc[8];
#pragma unroll
    for (int j = 0; j < 8; ++j) acc[j] = f32x4{0.f, 0.f, 0.f, 0.f};

    const int n0 = nt * 64;

    for (int c0 = 0; c0 < NC; c0 += 64) {
        __syncthreads();
#pragma unroll
        for (int p = 0; p < 4; ++p) {
            int cc = p * 16 + (tid >> 4);
            int nn = (tid & 15) * 4;
            f32x4 xv = *(const f32x4*)(x + ((size_t)b * NC + (c0 + cc)) * NN + n0 + nn);
#pragma unroll
            for (int e = 0; e < 4; ++e) {
                float f = xv[e];
                bf16 hh = (bf16)f;
                int row = nn + e;
                int off = (row * 128 + cc * 2) ^ ((row & 7) << 4);
                *(bf16*)(Ah + off) = hh;
                *(bf16*)(Al + off) = (bf16)(f - (float)hh);
            }
        }
#pragma unroll
        for (int p = 0; p < 8; ++p) {
            int i  = p * 16 + (tid >> 4);
            int c4 = (tid & 15) * 4;
            f32x4 w4 = *(const f32x4*)(W + (size_t)i * NC + c0 + c4);
            bf16x4 hv, lv;
#pragma unroll
            for (int e = 0; e < 4; ++e) {
                bf16 hh = (bf16)w4[e];
                hv[e] = hh;
                lv[e] = (bf16)(w4[e] - (float)hh);
            }
            int off = (i * 128 + c4 * 2) ^ ((i & 7) << 4);
            *(bf16x4*)(Wh + off) = hv;
            if (split) *(bf16x4*)(Wl + off) = lv;
        }
        __syncthreads();
#pragma unroll
        for (int kk = 0; kk < 2; ++kk) {
            int row  = wv * 16 + lq;
            int koff = kk * 64 + lg * 16;
            int aoff = (row * 128 + koff) ^ ((row & 7) << 4);
            bf16x8 ah = *(const bf16x8*)(Ah + aoff);
            bf16x8 al = *(const bf16x8*)(Al + aoff);
#pragma unroll
            for (int j = 0; j < 8; ++j) {
                int ir   = j * 16 + lq;
                int woff = (ir * 128 + koff) ^ ((ir & 7) << 4);
                bf16x8 bh = *(const bf16x8*)(Wh + woff);
                acc[j] = MFMA16(ah, bh, acc[j]);
                if (split) {
                    bf16x8 bl = *(const bf16x8*)(Wl + woff);
                    acc[j] = MFMA16(ah, bl, acc[j]);
                    acc[j] = MFMA16(al, bh, acc[j]);
                }
            }
        }
    }

    if (pj == 2) {
        // transpose in LDS, then write V fragment-major (16B/lane, coalesced)
        __syncthreads();
        char* T = lds;   // [128 i][64 n] bf16, swizzled
#pragma unroll
        for (int j = 0; j < 8; ++j) {
            int i = j * 16 + lq;
            float bv2 = bias[i];
#pragma unroll
            for (int r = 0; r < 4; ++r) {
                int nl = wv * 16 + lg * 4 + r;
                int off = (i * 128 + nl * 2) ^ ((i & 7) << 4);
                *(bf16*)(T + off) = (bf16)(acc[j][r] + bv2);
            }
        }
        __syncthreads();
#pragma unroll
        for (int p = 0; p < 4; ++p) {
            int i  = p * 32 + (tid >> 3);   // d channel 0..127
            int sl = tid & 7;               // m-octet 0..7
            i32x4 tv = *(const i32x4*)(T + ((i * 128 + sl * 16) ^ ((i & 7) << 4)));
            size_t off = (size_t)b * PBATCH
                       + (size_t)((((nt * 8 + (i >> 4)) * 2 + (sl >> 2)) * 64
                                   + (sl & 3) * 16 + (i & 15)) * 8);
            *(i32x4*)(vv + off) = tv;
        }
    } else {
        const float sc = (pj == 0) ? QSCALE : 1.0f;
#pragma unroll
        for (int j = 0; j < 8; ++j) {
            int i = j * 16 + lq;
            float bv2 = bias[i];
#pragma unroll
            for (int r = 0; r < 4; ++r) {
                int q = n0 + wv * 16 + lg * 4 + r;
                size_t off = ((size_t)b * NN + q) * NCI + i;
                float val = (acc[j][r] + bv2) * sc;
                bf16 hh = (bf16)val;
                bf16 ll = (bf16)(val - (float)hh);
                if (pj == 0) { qh[off] = hh; ql[off] = ll; }
                else         { kh[off] = hh; kl[off] = ll; }
            }
        }
    }
}

// ---------------------------------------------------------------------------
// Kernel 2: flash attention. 512 blocks x 256 thr (2 blocks/CU), 4 waves x
// 16 q, BK=64. K double-buffered in LDS with register prefetch (1 barrier per
// iter); V fragment-major direct from L2, loads pinned early by
// sched_barrier(0). exp2-domain softmax with defer-max.
// ---------------------------------------------------------------------------
__global__ __launch_bounds__(256, 2) void k_attn(
    const bf16* __restrict__ qh, const bf16* __restrict__ ql,
    const bf16* __restrict__ kh, const bf16* __restrict__ kl,
    const bf16* __restrict__ vf, bf16* __restrict__ y)
{
    const int bid = blockIdx.x;       // 0..511
    const int b   = bid & 7;          // batch == XCD (L2 colocation)
    const int qt  = bid >> 3;         // 0..63
    const int tid = threadIdx.x;
    const int wv  = tid >> 6;
    const int ln  = tid & 63;
    const int lg  = ln >> 4;          // 0..3
    const int lq  = ln & 15;
    const int n0  = qt * 64;

    // LDS: K buf0 32K | K buf1 32K | P 4x2K -> 72 KB (2 blocks/CU)
    __shared__ __attribute__((aligned(16))) char lds[73728];
    char* P = lds + 65536 + wv * 2048;   // per-wave [16 q][64 m] bf16, swizzled

    const int smm = tid >> 4;   // staging row within 16-row group
    const int ssl = tid & 15;   // staging 16B unit within 256B row

    // ---- Q fragments (loop-invariant). B-frag: col=lq=q, k=lg*8+e.
    bf16x8 qhf[4], qlf[4];
    {
        int qrow = n0 + wv * 16 + lq;
        const bf16* bh = qh + ((size_t)b * NN + qrow) * NCI;
        const bf16* bl = ql + ((size_t)b * NN + qrow) * NCI;
#pragma unroll
        for (int kk = 0; kk < 4; ++kk) {
            int d0 = kk * 32 + lg * 8;
            qhf[kk] = *(const bf16x8*)(bh + d0);
            qlf[kk] = *(const bf16x8*)(bl + d0);
        }
    }

    f32x4 o[8];
#pragma unroll
    for (int j = 0; j < 8; ++j) o[j] = f32x4{0.f, 0.f, 0.f, 0.f};
    float mrun = -1e30f, lrun = 0.f;

    // V fragment-major base: + lane*16B (coalesced)
    const bf16* vb = vf + (size_t)b * PBATCH + (size_t)ln * 8;

    // ---- prologue: stage K tile 0 into buf0
    {
#pragma unroll
        for (int p = 0; p < 4; ++p) {
            int mm = p * 16 + smm;
            size_t g = ((size_t)b * NN + mm) * NCI + ssl * 8;
            i32x4 hv = *(const i32x4*)(kh + g);
            i32x4 lv = *(const i32x4*)(kl + g);
            int off = (mm * 256 + ssl * 16) ^ ((mm & 7) << 4);
            *(i32x4*)(lds + off) = hv;
            *(i32x4*)(lds + 16384 + off) = lv;
        }
    }
    __syncthreads();

    for (int t = 0; t < 64; ++t) {
        const int cur = t & 1;
        char* KHc = lds + cur * 32768;
        char* KLc = KHc + 16384;
        char* KHn = lds + (cur ^ 1) * 32768;
        char* KLn = KHn + 16384;
        const bool pre = (t < 63);

        // ---- issue K[t+1] prefetch loads (hide under QK^T)
        i32x4 rkh[4], rkl[4];
        if (pre) {
#pragma unroll
            for (int p = 0; p < 4; ++p) {
                size_t g = ((size_t)b * NN + (t + 1) * 64 + p * 16 + smm) * NCI + ssl * 8;
                rkh[p] = *(const i32x4*)(kh + g);
                rkl[p] = *(const i32x4*)(kl + g);
            }
        }
        // ---- issue V[t] fragment loads (consumed in PV)
        bf16x8 bv[8][2];
        {
            const bf16* vp = vb + (size_t)t * 8192;
#pragma unroll
            for (int j = 0; j < 8; ++j) {
                bv[j][0] = *(const bf16x8*)(vp + (j * 2 + 0) * 512);
                bv[j][1] = *(const bf16x8*)(vp + (j * 2 + 1) * 512);
            }
        }
        // pin the loads here: forbid the scheduler from sinking them to uses
        __builtin_amdgcn_sched_barrier(0);

        // ---- swapped QK^T: S^T[m][q], A=K (LDS), B=Q (regs), split 3-MFMA
        f32x4 s[4];
        __builtin_amdgcn_s_setprio(1);
#pragma unroll
        for (int jm = 0; jm < 4; ++jm) {
            s[jm] = f32x4{0.f, 0.f, 0.f, 0.f};
            const int mrow = jm * 16 + lq;
            const int sw = (mrow & 7) << 4;
#pragma unroll
            for (int kk = 0; kk < 4; ++kk) {
                int aoff = (mrow * 256 + kk * 64 + lg * 16) ^ sw;
                bf16x8 ah = *(const bf16x8*)(KHc + aoff);
                bf16x8 al = *(const bf16x8*)(KLc + aoff);
                s[jm] = MFMA16(ah, qhf[kk], s[jm]);
                s[jm] = MFMA16(al, qhf[kk], s[jm]);
                s[jm] = MFMA16(ah, qlf[kk], s[jm]);
            }
        }
        __builtin_amdgcn_s_setprio(0);

        // ---- write K[t+1] into the alternate buffer (reads of cur done)
        if (pre) {
#pragma unroll
            for (int p = 0; p < 4; ++p) {
                int mm = p * 16 + smm;
                int off = (mm * 256 + ssl * 16) ^ ((mm & 7) << 4);
                *(i32x4*)(KHn + off) = rkh[p];
                *(i32x4*)(KLn + off) = rkl[p];
            }
        }

        // ---- online softmax (exp2 domain). Lane owns column q = lq.
        float tm = s[0][0];
#pragma unroll
        for (int jm = 0; jm < 4; ++jm)
#pragma unroll
            for (int r = 0; r < 4; ++r) tm = fmaxf(tm, s[jm][r]);
        tm = fmaxf(tm, __shfl_xor(tm, 16));
        tm = fmaxf(tm, __shfl_xor(tm, 32));

        // defer-max: rescale only when running max grows by > 8 (log2 units)
        if (__any(tm > mrun + 8.f)) {
            float mnew = fmaxf(mrun, tm);
            float alpha = exp2f(mrun - mnew);
            mrun = mnew;
            lrun *= alpha;
            float av[4];
#pragma unroll
            for (int r = 0; r < 4; ++r) av[r] = __shfl(alpha, lg * 4 + r);
#pragma unroll
            for (int j = 0; j < 8; ++j)
#pragma unroll
                for (int r = 0; r < 4; ++r) o[j][r] *= av[r];
        }

        // ---- P = exp2(S - m), packed bf16x4 writes to per-wave LDS
        float psum = 0.f;
#pragma unroll
        for (int jm = 0; jm < 4; ++jm) {
            bf16x4 pk;
#pragma unroll
            for (int r = 0; r < 4; ++r) {
                float e2 = exp2f(s[jm][r] - mrun);
                psum += e2;
                pk[r] = (bf16)e2;
            }
            int off = (lq * 128 + (jm * 16 + lg * 4) * 2) ^ ((lq & 7) << 4);
            *(bf16x4*)(P + off) = pk;
        }
        psum += __shfl_xor(psum, 16);
        psum += __shfl_xor(psum, 32);
        lrun += psum;

        // ---- PV: O[q][d] += P[q][m] * V[m][d]; A=P (LDS), B=V (regs, L2)
        bf16x8 pa[2];
#pragma unroll
        for (int tt = 0; tt < 2; ++tt)
            pa[tt] = *(const bf16x8*)(P + ((lq * 128 + tt * 64 + lg * 16) ^ ((lq & 7) << 4)));
        __builtin_amdgcn_s_setprio(1);
#pragma unroll
        for (int j = 0; j < 8; ++j) {
            o[j] = MFMA16(pa[0], bv[j][0], o[j]);
            o[j] = MFMA16(pa[1], bv[j][1], o[j]);
        }
        __builtin_amdgcn_s_setprio(0);

        __syncthreads();   // K[t+1] visible; all reads of buf[cur] complete
    }

    // ---- epilogue: y = O / l
    float rl[4];
#pragma unroll
    for (int r = 0; r < 4; ++r) rl[r] = 1.f / __shfl(lrun, lg * 4 + r);
#pragma unroll
    for (int j = 0; j < 8; ++j) {
        int d = j * 16 + lq;
#pragma unroll
        for (int r = 0; r < 4; ++r) {
            int q = n0 + wv * 16 + lg * 4 + r;
            y[((size_t)b * NN + q) * NCI + d] = (bf16)(o[j][r] * rl[r]);
        }
    }
}

// ---------------------------------------------------------------------------
// Kernel 3: out[b,c,n] = x[b,c,n] + sum_i y[b,n,i]*w_out[c,i] + b_out[c]
// ---------------------------------------------------------------------------
__global__ __launch_bounds__(256) void k_out(
    const bf16* __restrict__ y, const float* __restrict__ x,
    const float* __restrict__ w_out, const float* __restrict__ b_out,
    float* __restrict__ out)
{
    const int nt  = blockIdx.x;
    const int b   = blockIdx.y;
    const int tid = threadIdx.x;
    const int wv  = tid >> 6;
    const int ln  = tid & 63;
    const int lg  = ln >> 4;
    const int lq  = ln & 15;
    const int n0  = nt * 64;

    __shared__ char Y[16384];   // [64 n][128 i] bf16, swizzled
#pragma unroll
    for (int p = 0; p < 4; ++p) {
        int nn = p * 16 + (tid >> 4);
        int d0 = (tid & 15) * 8;
        i32x4 t = *(const i32x4*)(y + ((size_t)b * NN + n0 + nn) * NCI + d0);
        *(i32x4*)(Y + ((nn * 256 + d0 * 2) ^ ((nn & 7) << 4))) = t;
    }
    __syncthreads();

    bf16x8 af[4];
    {
        int row = wv * 16 + lq;
#pragma unroll
        for (int kk = 0; kk < 4; ++kk) {
            int koff = kk * 64 + lg * 16;
            af[kk] = *(const bf16x8*)(Y + ((row * 256 + koff) ^ ((row & 7) << 4)));
        }
    }

    f32x4 acc[16];
#pragma unroll
    for (int j = 0; j < 16; ++j) acc[j] = f32x4{0.f, 0.f, 0.f, 0.f};

#pragma unroll
    for (int j = 0; j < 16; ++j) {
        int c = j * 16 + lq;
#pragma unroll
        for (int kk = 0; kk < 4; ++kk) {
            int i0 = kk * 32 + lg * 8;
            f32x4 wa = *(const f32x4*)(w_out + (size_t)c * NCI + i0);
            f32x4 wb = *(const f32x4*)(w_out + (size_t)c * NCI + i0 + 4);
            bf16x8 bw;
#pragma unroll
            for (int e = 0; e < 4; ++e) { bw[e] = (bf16)wa[e]; bw[e + 4] = (bf16)wb[e]; }
            acc[j] = MFMA16(af[kk], bw, acc[j]);
        }
    }

#pragma unroll
    for (int j = 0; j < 16; ++j) {
        int c = j * 16 + lq;
        int nb = n0 + wv * 16 + lg * 4;
        size_t off = ((size_t)b * NC + c) * (size_t)NN + nb;
        f32x4 xv = *(const f32x4*)(x + off);
        float bo = b_out[c];
        f32x4 r;
#pragma unroll
        for (int t = 0; t < 4; ++t) r[t] = acc[j][t] + xv[t] + bo;
        *(f32x4*)(out + off) = r;
    }
}

// ---------------------------------------------------------------------------
extern "C" void kernel_launch(void* const* d_in, const int* in_sizes, int n_in,
                              void* d_out, int out_size, void* d_ws, size_t ws_size,
                              hipStream_t stream)
{
    (void)in_sizes; (void)n_in; (void)out_size; (void)ws_size;
    const float* x  = (const float*)d_in[0];
    const float* wg = (const float*)d_in[1];
    const float* bg = (const float*)d_in[2];
    const float* wt = (const float*)d_in[3];
    const float* bt = (const float*)d_in[4];
    const float* wp = (const float*)d_in[5];
    const float* bp = (const float*)d_in[6];
    const float* wo = (const float*)d_in[7];
    const float* bo = (const float*)d_in[8];
    float* out = (float*)d_out;

    char* ws = (char*)d_ws;
    bf16* qh = (bf16*)(ws);
    bf16* ql = (bf16*)(ws + NEL * 2);
    bf16* kh = (bf16*)(ws + NEL * 4);    // standard [b][m][d] hi
    bf16* kl = (bf16*)(ws + NEL * 6);    // standard [b][m][d] lo
    bf16* vv = (bf16*)(ws + NEL * 8);    // fragment-major V
    bf16* y  = qh;   // safe: k_attn reads its own Q rows before writing them

    k_proj<<<dim3(64, 3, 8), 256, 0, stream>>>(x, wt, bt, wp, bp, wg, bg,
                                               qh, ql, kh, kl, vv);
    k_attn<<<dim3(512), 256, 0, stream>>>(qh, ql, kh, kl, vv, y);
    k_out<<<dim3(64, 8), 256, 0, stream>>>(y, x, wo, bo, out);
}

// Round 9
// 249.455 us; speedup vs baseline: 1.7780x; 1.0228x over previous
//
#include <hip/hip_runtime.h>
#include <hip/hip_bf16.h>
#include <stdint.h>
#include <stddef.h>

// ---------------------------------------------------------------------------
// NonLocalBlock2D: B=8, C=256, H=W=64 (N=4096), CI=128
// out = x + Wout * softmax( (theta(x)^T phi(x)) * sqrt(CI) ) * g(x)
// Split-fp32 (bf16 hi+lo, 3-MFMA) upstream of softmax; plain bf16 after.
// theta pre-scaled by sqrt(128)/ln2 -> softmax in exp2 domain.
// K standard [b][m][d] hi/lo, double-buffered LDS, reg prefetch, 1 barrier
// per iter; V fragment-major, coalesced dwordx4 direct from L2.
// k_attn_sp: 1024 blocks x 128 thr (4 blocks/CU), 2 waves x 32 q, BK=32,
// KV-split x2 (flash-decoding), k_comb merges halves.
// ---------------------------------------------------------------------------

typedef __bf16 bf16;
typedef __attribute__((ext_vector_type(8))) __bf16 bf16x8;
typedef __attribute__((ext_vector_type(4))) __bf16 bf16x4;
typedef __attribute__((ext_vector_type(4))) float  f32x4;
typedef __attribute__((ext_vector_type(4))) int    i32x4;

#define MFMA16(a, b, c) __builtin_amdgcn_mfma_f32_16x16x32_bf16((a), (b), (c), 0, 0, 0)

constexpr int NB  = 8;
constexpr int NC  = 256;
constexpr int NN  = 4096;
constexpr int NCI = 128;
constexpr size_t NEL = (size_t)NB * NN * NCI;
constexpr int PBATCH = NN * NCI;       // elems per batch

// sqrt(128) / ln(2): folded into theta so logits are in log2 units.
#define QSCALE (11.313708498984761f * 1.4426950408889634f)

// V fragment layout (16x16x32 MFMA B-operand):
//  Vf[b][m>>6][j=d>>4][tt=(m&63)>>5][lane][8], lane=((m>>3)&3)*16+(d&15), e=m&7

// ---------------------------------------------------------------------------
// Kernel 1: projections.  pj=0 -> theta*QSCALE (std, split qh/ql),
// pj=1 -> phi (std, split kh/kl), pj=2 -> g -> fragment-major vv.
// ---------------------------------------------------------------------------
__global__ __launch_bounds__(256) void k_proj(
    const float* __restrict__ x,
    const float* __restrict__ wt, const float* __restrict__ bt,
    const float* __restrict__ wp, const float* __restrict__ bp,
    const float* __restrict__ wg, const float* __restrict__ bg,
    bf16* __restrict__ qh, bf16* __restrict__ ql,
    bf16* __restrict__ kh, bf16* __restrict__ kl,
    bf16* __restrict__ vv)
{
    const int nt  = blockIdx.x;      // 0..63
    const int pj  = blockIdx.y;      // 0..2
    const int b   = blockIdx.z;      // 0..7
    const int tid = threadIdx.x;
    const int wv  = tid >> 6;
    const int ln  = tid & 63;
    const int lg  = ln >> 4;
    const int lq  = ln & 15;

    const float* W;
    const float* bias;
    if (pj == 0)      { W = wt; bias = bt; }
    else if (pj == 1) { W = wp; bias = bp; }
    else              { W = wg; bias = bg; }
    const bool split = (pj != 2);

    __shared__ char lds[49152];
    char* Ah = lds;            // [64 n][64 c] bf16 hi, swizzled
    char* Al = lds + 8192;
    char* Wh = lds + 16384;    // [128 i][64 c] bf16 hi, swizzled
    char* Wl = lds + 32768;

    f32x4 acc[8];
#pragma unroll
    for (int j = 0; j < 8; ++j) acc[j] = f32x4{0.f, 0.f, 0.f, 0.f};

    const int n0 = nt * 64;

    for (int c0 = 0; c0 < NC; c0 += 64) {
        __syncthreads();
#pragma unroll
        for (int p = 0; p < 4; ++p) {
            int cc = p * 16 + (tid >> 4);
            int nn = (tid & 15) * 4;
            f32x4 xv = *(const f32x4*)(x + ((size_t)b * NC + (c0 + cc)) * NN + n0 + nn);
#pragma unroll
            for (int e = 0; e < 4; ++e) {
                float f = xv[e];
                bf16 hh = (bf16)f;
                int row = nn + e;
                int off = (row * 128 + cc * 2) ^ ((row & 7) << 4);
                *(bf16*)(Ah + off) = hh;
                *(bf16*)(Al + off) = (bf16)(f - (float)hh);
            }
        }
#pragma unroll
        for (int p = 0; p < 8; ++p) {
            int i  = p * 16 + (tid >> 4);
            int c4 = (tid & 15) * 4;
            f32x4 w4 = *(const f32x4*)(W + (size_t)i * NC + c0 + c4);
            bf16x4 hv, lv;
#pragma unroll
            for (int e = 0; e < 4; ++e) {
                bf16 hh = (bf16)w4[e];
                hv[e] = hh;
                lv[e] = (bf16)(w4[e] - (float)hh);
            }
            int off = (i * 128 + c4 * 2) ^ ((i & 7) << 4);
            *(bf16x4*)(Wh + off) = hv;
            if (split) *(bf16x4*)(Wl + off) = lv;
        }
        __syncthreads();
#pragma unroll
        for (int kk = 0; kk < 2; ++kk) {
            int row  = wv * 16 + lq;
            int koff = kk * 64 + lg * 16;
            int aoff = (row * 128 + koff) ^ ((row & 7) << 4);
            bf16x8 ah = *(const bf16x8*)(Ah + aoff);
            bf16x8 al = *(const bf16x8*)(Al + aoff);
#pragma unroll
            for (int j = 0; j < 8; ++j) {
                int ir   = j * 16 + lq;
                int woff = (ir * 128 + koff) ^ ((ir & 7) << 4);
                bf16x8 bh = *(const bf16x8*)(Wh + woff);
                acc[j] = MFMA16(ah, bh, acc[j]);
                if (split) {
                    bf16x8 bl = *(const bf16x8*)(Wl + woff);
                    acc[j] = MFMA16(ah, bl, acc[j]);
                    acc[j] = MFMA16(al, bh, acc[j]);
                }
            }
        }
    }

    if (pj == 2) {
        // transpose in LDS, then write V fragment-major (16B/lane, coalesced)
        __syncthreads();
        char* T = lds;   // [128 i][64 n] bf16, swizzled
#pragma unroll
        for (int j = 0; j < 8; ++j) {
            int i = j * 16 + lq;
            float bv2 = bias[i];
#pragma unroll
            for (int r = 0; r < 4; ++r) {
                int nl = wv * 16 + lg * 4 + r;
                int off = (i * 128 + nl * 2) ^ ((i & 7) << 4);
                *(bf16*)(T + off) = (bf16)(acc[j][r] + bv2);
            }
        }
        __syncthreads();
#pragma unroll
        for (int p = 0; p < 4; ++p) {
            int i  = p * 32 + (tid >> 3);   // d channel 0..127
            int sl = tid & 7;               // m-octet 0..7
            i32x4 tv = *(const i32x4*)(T + ((i * 128 + sl * 16) ^ ((i & 7) << 4)));
            size_t off = (size_t)b * PBATCH
                       + (size_t)((((nt * 8 + (i >> 4)) * 2 + (sl >> 2)) * 64
                                   + (sl & 3) * 16 + (i & 15)) * 8);
            *(i32x4*)(vv + off) = tv;
        }
    } else {
        const float sc = (pj == 0) ? QSCALE : 1.0f;
#pragma unroll
        for (int j = 0; j < 8; ++j) {
            int i = j * 16 + lq;
            float bv2 = bias[i];
#pragma unroll
            for (int r = 0; r < 4; ++r) {
                int q = n0 + wv * 16 + lg * 4 + r;
                size_t off = ((size_t)b * NN + q) * NCI + i;
                float val = (acc[j][r] + bv2) * sc;
                bf16 hh = (bf16)val;
                bf16 ll = (bf16)(val - (float)hh);
                if (pj == 0) { qh[off] = hh; ql[off] = ll; }
                else         { kh[off] = hh; kl[off] = ll; }
            }
        }
    }
}

// ---------------------------------------------------------------------------
// Kernel 2: flash attention, 32 q/wave. 1024 blocks x 128 thr (4 blocks/CU),
// 2 waves x 32 q, BK=32, KV-split x2. K double-buffered LDS + reg prefetch
// (1 barrier/iter); V fragment-major direct from L2.
// ---------------------------------------------------------------------------
__global__ __launch_bounds__(128, 2) void k_attn_sp(
    const bf16* __restrict__ qh, const bf16* __restrict__ ql,
    const bf16* __restrict__ kh, const bf16* __restrict__ kl,
    const bf16* __restrict__ vf,
    bf16* __restrict__ p0, bf16* __restrict__ p1, float* __restrict__ ml)
{
    const int bid = blockIdx.x;       // 0..1023
    const int b   = bid & 7;          // batch == XCD (L2 colocation)
    const int rs  = bid >> 3;         // 0..127
    const int qt  = rs & 63;          // 0..63
    const int h   = rs >> 6;          // 0..1  (KV half)
    const int tid = threadIdx.x;      // 0..127
    const int wv  = tid >> 6;         // 0..1
    const int ln  = tid & 63;
    const int lg  = ln >> 4;          // 0..3
    const int lq  = ln & 15;
    const int n0  = qt * 64;
    const int mb0 = h * 2048;
    bf16* ph = h ? p1 : p0;

    // LDS: Kbuf0 16K (KH 8K + KL 8K) | Kbuf1 16K | P 2x2K -> 36 KB
    __shared__ __attribute__((aligned(16))) char lds[36864];
    char* P = lds + 32768 + wv * 2048;   // per-wave [32 q][32 m] bf16, swizzled

    const int smm = tid >> 4;   // staging row within 8-row group (0..7)
    const int ssl = tid & 15;   // staging 16B unit within 256B row

    // ---- Q fragments (2 q-subtiles x 4 k-chunks), hi/lo, loop-invariant
    bf16x8 qhf[2][4], qlf[2][4];
#pragma unroll
    for (int q2 = 0; q2 < 2; ++q2) {
        int qrow = n0 + wv * 32 + q2 * 16 + lq;
        const bf16* bh = qh + ((size_t)b * NN + qrow) * NCI;
        const bf16* bl = ql + ((size_t)b * NN + qrow) * NCI;
#pragma unroll
        for (int kk = 0; kk < 4; ++kk) {
            qhf[q2][kk] = *(const bf16x8*)(bh + kk * 32 + lg * 8);
            qlf[q2][kk] = *(const bf16x8*)(bl + kk * 32 + lg * 8);
        }
    }

    f32x4 o[2][8];
#pragma unroll
    for (int q2 = 0; q2 < 2; ++q2)
#pragma unroll
        for (int j = 0; j < 8; ++j) o[q2][j] = f32x4{0.f, 0.f, 0.f, 0.f};
    float mrun[2] = {-1e30f, -1e30f};
    float lrun[2] = {0.f, 0.f};

    // V fragment-major base: + lane*16B (coalesced)
    const bf16* vb = vf + (size_t)b * PBATCH + (size_t)ln * 8;

    // ---- prologue: stage K tile 0 (32 m) into buf0
    {
#pragma unroll
        for (int p = 0; p < 4; ++p) {
            int mm = p * 8 + smm;
            size_t g = ((size_t)b * NN + mb0 + mm) * NCI + ssl * 8;
            i32x4 hv = *(const i32x4*)(kh + g);
            i32x4 lv = *(const i32x4*)(kl + g);
            int off = (mm * 256 + ssl * 16) ^ ((mm & 7) << 4);
            *(i32x4*)(lds + off) = hv;
            *(i32x4*)(lds + 8192 + off) = lv;
        }
    }
    __syncthreads();

    for (int t = 0; t < 64; ++t) {
        const int cur = t & 1;
        char* KHc = lds + cur * 16384;
        char* KLc = KHc + 8192;
        char* KHn = lds + (cur ^ 1) * 16384;
        char* KLn = KHn + 8192;
        const bool pre = (t < 63);

        // ---- issue K[t+1] prefetch loads (hide under QK^T)
        i32x4 rkh[4], rkl[4];
        if (pre) {
#pragma unroll
            for (int p = 0; p < 4; ++p) {
                size_t g = ((size_t)b * NN + mb0 + (t + 1) * 32 + p * 8 + smm) * NCI + ssl * 8;
                rkh[p] = *(const i32x4*)(kh + g);
                rkl[p] = *(const i32x4*)(kl + g);
            }
        }
        __builtin_amdgcn_sched_barrier(0);

        // ---- swapped QK^T: S^T[32 m][32 q], A=K (LDS), B=Q (regs), 3-MFMA
        f32x4 s[2][2];
        __builtin_amdgcn_s_setprio(1);
#pragma unroll
        for (int jm = 0; jm < 2; ++jm) {
            s[jm][0] = f32x4{0.f, 0.f, 0.f, 0.f};
            s[jm][1] = f32x4{0.f, 0.f, 0.f, 0.f};
            const int mrow = jm * 16 + lq;
            const int sw = (mrow & 7) << 4;
#pragma unroll
            for (int kk = 0; kk < 4; ++kk) {
                int aoff = (mrow * 256 + kk * 64 + lg * 16) ^ sw;
                bf16x8 ah = *(const bf16x8*)(KHc + aoff);
                bf16x8 al = *(const bf16x8*)(KLc + aoff);
                s[jm][0] = MFMA16(ah, qhf[0][kk], s[jm][0]);
                s[jm][1] = MFMA16(ah, qhf[1][kk], s[jm][1]);
                s[jm][0] = MFMA16(al, qhf[0][kk], s[jm][0]);
                s[jm][1] = MFMA16(al, qhf[1][kk], s[jm][1]);
                s[jm][0] = MFMA16(ah, qlf[0][kk], s[jm][0]);
                s[jm][1] = MFMA16(ah, qlf[1][kk], s[jm][1]);
            }
        }
        __builtin_amdgcn_s_setprio(0);

        // ---- issue V[t] fragment loads (latency hides under softmax)
        bf16x8 bv[8];
        {
            const bf16* vp = vb + (size_t)(h * 32 + (t >> 1)) * 8192;
#pragma unroll
            for (int j = 0; j < 8; ++j)
                bv[j] = *(const bf16x8*)(vp + (j * 2 + (t & 1)) * 512);
        }
        __builtin_amdgcn_sched_barrier(0);

        // ---- write K[t+1] into the alternate buffer (reads of cur done)
        if (pre) {
#pragma unroll
            for (int p = 0; p < 4; ++p) {
                int mm = p * 8 + smm;
                int off = (mm * 256 + ssl * 16) ^ ((mm & 7) << 4);
                *(i32x4*)(KHn + off) = rkh[p];
                *(i32x4*)(KLn + off) = rkl[p];
            }
        }

        // ---- online softmax (exp2 domain). Lane owns columns q2*16+lq.
        float tm[2];
        tm[0] = s[0][0][0];
        tm[1] = s[0][1][0];
#pragma unroll
        for (int jm = 0; jm < 2; ++jm)
#pragma unroll
            for (int r = 0; r < 4; ++r) {
                tm[0] = fmaxf(tm[0], s[jm][0][r]);
                tm[1] = fmaxf(tm[1], s[jm][1][r]);
            }
#pragma unroll
        for (int q2 = 0; q2 < 2; ++q2) {
            tm[q2] = fmaxf(tm[q2], __shfl_xor(tm[q2], 16));
            tm[q2] = fmaxf(tm[q2], __shfl_xor(tm[q2], 32));
        }

        // defer-max: rescale only when running max grows by > 8 (log2 units)
        bool grow = (tm[0] > mrun[0] + 8.f) || (tm[1] > mrun[1] + 8.f);
        if (__any(grow)) {
            float alpha[2];
#pragma unroll
            for (int q2 = 0; q2 < 2; ++q2) {
                float mnew = fmaxf(mrun[q2], tm[q2]);
                alpha[q2] = exp2f(mrun[q2] - mnew);
                mrun[q2] = mnew;
                lrun[q2] *= alpha[q2];
            }
            float av0[4], av1[4];
#pragma unroll
            for (int r = 0; r < 4; ++r) {
                av0[r] = __shfl(alpha[0], lg * 4 + r);
                av1[r] = __shfl(alpha[1], lg * 4 + r);
            }
#pragma unroll
            for (int j = 0; j < 8; ++j)
#pragma unroll
                for (int r = 0; r < 4; ++r) {
                    o[0][j][r] *= av0[r];
                    o[1][j][r] *= av1[r];
                }
        }

        // ---- P = exp2(S - m), packed bf16x4 writes to per-wave LDS
        float psum[2] = {0.f, 0.f};
#pragma unroll
        for (int jm = 0; jm < 2; ++jm)
#pragma unroll
            for (int q2 = 0; q2 < 2; ++q2) {
                bf16x4 pk;
#pragma unroll
                for (int r = 0; r < 4; ++r) {
                    float e2 = exp2f(s[jm][q2][r] - mrun[q2]);
                    psum[q2] += e2;
                    pk[r] = (bf16)e2;
                }
                int row = q2 * 16 + lq;
                int off = (row * 64 + (jm * 16 + lg * 4) * 2) ^ ((row & 7) << 4);
                *(bf16x4*)(P + off) = pk;
            }
#pragma unroll
        for (int q2 = 0; q2 < 2; ++q2) {
            psum[q2] += __shfl_xor(psum[q2], 16);
            psum[q2] += __shfl_xor(psum[q2], 32);
            lrun[q2] += psum[q2];
        }

        // ---- PV: O[q][d] += P[q][m] * V[m][d]; A=P (LDS), B=V (regs, L2)
        bf16x8 pa[2];
#pragma unroll
        for (int q2 = 0; q2 < 2; ++q2) {
            int row = q2 * 16 + lq;
            pa[q2] = *(const bf16x8*)(P + ((row * 64 + lg * 16) ^ ((row & 7) << 4)));
        }
        __builtin_amdgcn_s_setprio(1);
#pragma unroll
        for (int j = 0; j < 8; ++j) {
            o[0][j] = MFMA16(pa[0], bv[j], o[0][j]);
            o[1][j] = MFMA16(pa[1], bv[j], o[1][j]);
        }
        __builtin_amdgcn_s_setprio(0);

        __syncthreads();   // K[t+1] visible; all reads of buf[cur] complete
    }

    // ---- epilogue: partial y_h = O / l (bf16), plus (m, l) per row
    float rl0[4], rl1[4];
#pragma unroll
    for (int r = 0; r < 4; ++r) {
        rl0[r] = 1.f / __shfl(lrun[0], lg * 4 + r);
        rl1[r] = 1.f / __shfl(lrun[1], lg * 4 + r);
    }
#pragma unroll
    for (int j = 0; j < 8; ++j) {
        int d = j * 16 + lq;
#pragma unroll
        for (int r = 0; r < 4; ++r) {
            int q0 = n0 + wv * 32 + lg * 4 + r;
            ph[((size_t)b * NN + q0) * NCI + d]      = (bf16)(o[0][j][r] * rl0[r]);
            ph[((size_t)b * NN + q0 + 16) * NCI + d] = (bf16)(o[1][j][r] * rl1[r]);
        }
    }
    if (lg == 0) {
#pragma unroll
        for (int q2 = 0; q2 < 2; ++q2) {
            int row = n0 + wv * 32 + q2 * 16 + lq;
            size_t base = ((size_t)b * NN + row) * 4 + h * 2;
            ml[base]     = mrun[q2];   // log2 domain
            ml[base + 1] = lrun[q2];
        }
    }
}

// ---------------------------------------------------------------------------
// Kernel 2b: combine the two KV-halves (exp2 domain).
// ---------------------------------------------------------------------------
__global__ __launch_bounds__(256) void k_comb(
    const bf16* __restrict__ p0, const bf16* __restrict__ p1,
    const float* __restrict__ ml, bf16* __restrict__ y)
{
    int row = blockIdx.x * 16 + (threadIdx.x >> 4);
    int d0  = (threadIdx.x & 15) * 8;
    f32x4 q = *(const f32x4*)(ml + (size_t)row * 4);  // m0 l0 m1 l1
    float M  = fmaxf(q[0], q[2]);
    float w0 = exp2f(q[0] - M) * q[1];
    float w1 = exp2f(q[2] - M) * q[3];
    float inv = 1.f / (w0 + w1);
    w0 *= inv; w1 *= inv;
    size_t off = (size_t)row * NCI + d0;
    bf16x8 a = *(const bf16x8*)(p0 + off);
    bf16x8 c = *(const bf16x8*)(p1 + off);
    bf16x8 r;
#pragma unroll
    for (int e = 0; e < 8; ++e) r[e] = (bf16)(w0 * (float)a[e] + w1 * (float)c[e]);
    *(bf16x8*)(y + off) = r;
}

// ---------------------------------------------------------------------------
// Kernel 3: out[b,c,n] = x[b,c,n] + sum_i y[b,n,i]*w_out[c,i] + b_out[c]
// ---------------------------------------------------------------------------
__global__ __launch_bounds__(256) void k_out(
    const bf16* __restrict__ y, const float* __restrict__ x,
    const float* __restrict__ w_out, const float* __restrict__ b_out,
    float* __restrict__ out)
{
    const int nt  = blockIdx.x;
    const int b   = blockIdx.y;
    const int tid = threadIdx.x;
    const int wv  = tid >> 6;
    const int ln  = tid & 63;
    const int lg  = ln >> 4;
    const int lq  = ln & 15;
    const int n0  = nt * 64;

    __shared__ char Y[16384];   // [64 n][128 i] bf16, swizzled
#pragma unroll
    for (int p = 0; p < 4; ++p) {
        int nn = p * 16 + (tid >> 4);
        int d0 = (tid & 15) * 8;
        i32x4 t = *(const i32x4*)(y + ((size_t)b * NN + n0 + nn) * NCI + d0);
        *(i32x4*)(Y + ((nn * 256 + d0 * 2) ^ ((nn & 7) << 4))) = t;
    }
    __syncthreads();

    bf16x8 af[4];
    {
        int row = wv * 16 + lq;
#pragma unroll
        for (int kk = 0; kk < 4; ++kk) {
            int koff = kk * 64 + lg * 16;
            af[kk] = *(const bf16x8*)(Y + ((row * 256 + koff) ^ ((row & 7) << 4)));
        }
    }

    f32x4 acc[16];
#pragma unroll
    for (int j = 0; j < 16; ++j) acc[j] = f32x4{0.f, 0.f, 0.f, 0.f};

#pragma unroll
    for (int j = 0; j < 16; ++j) {
        int c = j * 16 + lq;
#pragma unroll
        for (int kk = 0; kk < 4; ++kk) {
            int i0 = kk * 32 + lg * 8;
            f32x4 wa = *(const f32x4*)(w_out + (size_t)c * NCI + i0);
            f32x4 wb = *(const f32x4*)(w_out + (size_t)c * NCI + i0 + 4);
            bf16x8 bw;
#pragma unroll
            for (int e = 0; e < 4; ++e) { bw[e] = (bf16)wa[e]; bw[e + 4] = (bf16)wb[e]; }
            acc[j] = MFMA16(af[kk], bw, acc[j]);
        }
    }

#pragma unroll
    for (int j = 0; j < 16; ++j) {
        int c = j * 16 + lq;
        int nb = n0 + wv * 16 + lg * 4;
        size_t off = ((size_t)b * NC + c) * (size_t)NN + nb;
        f32x4 xv = *(const f32x4*)(x + off);
        float bo = b_out[c];
        f32x4 r;
#pragma unroll
        for (int t = 0; t < 4; ++t) r[t] = acc[j][t] + xv[t] + bo;
        *(f32x4*)(out + off) = r;
    }
}

// ---------------------------------------------------------------------------
extern "C" void kernel_launch(void* const* d_in, const int* in_sizes, int n_in,
                              void* d_out, int out_size, void* d_ws, size_t ws_size,
                              hipStream_t stream)
{
    (void)in_sizes; (void)n_in; (void)out_size; (void)ws_size;
    const float* x  = (const float*)d_in[0];
    const float* wg = (const float*)d_in[1];
    const float* bg = (const float*)d_in[2];
    const float* wt = (const float*)d_in[3];
    const float* bt = (const float*)d_in[4];
    const float* wp = (const float*)d_in[5];
    const float* bp = (const float*)d_in[6];
    const float* wo = (const float*)d_in[7];
    const float* bo = (const float*)d_in[8];
    float* out = (float*)d_out;

    char* ws = (char*)d_ws;
    bf16* qh = (bf16*)(ws);
    bf16* ql = (bf16*)(ws + NEL * 2);
    bf16* kh = (bf16*)(ws + NEL * 4);    // standard [b][m][d] hi
    bf16* kl = (bf16*)(ws + NEL * 6);    // standard [b][m][d] lo
    bf16* vv = (bf16*)(ws + NEL * 8);    // fragment-major V
    bf16* y  = qh;                       // safe: k_comb writes after qh reads
    bf16* p0 = (bf16*)(ws + NEL * 10);   // KV-split partials
    bf16* p1 = (bf16*)(ws + NEL * 12);
    float* ml = (float*)(ws + NEL * 14); // ws >= 59 MB proven (R4 ran split path)

    k_proj<<<dim3(64, 3, 8), 256, 0, stream>>>(x, wt, bt, wp, bp, wg, bg,
                                               qh, ql, kh, kl, vv);
    k_attn_sp<<<dim3(1024), 128, 0, stream>>>(qh, ql, kh, kl, vv, p0, p1, ml);
    k_comb<<<dim3(2048), 256, 0, stream>>>(p0, p1, ml, y);
    k_out<<<dim3(64, 8), 256, 0, stream>>>(y, x, wo, bo, out);
}